// Round 17
// baseline (98.721 us; speedup 1.0000x reference)
//
#include <hip/hip_runtime.h>
#include <stdint.h>

typedef __attribute__((ext_vector_type(8))) short bf16x8;
typedef __attribute__((ext_vector_type(4))) float f32x4;
typedef __attribute__((ext_vector_type(4))) unsigned int u32x4;

#define NB 2
#define NL 2048
#define ND 768
#define NH 12
#define NDK 64
#define NM 4096   // NB*NL
#define LOG2E 1.4426950408889634f

template<int N> struct IC { static constexpr int v = N; };

__device__ __forceinline__ unsigned short f2bf(float f) {
  unsigned u = __builtin_bit_cast(unsigned, f);
  u += 0x7FFFu + ((u >> 16) & 1u);          // RNE
  return (unsigned short)(u >> 16);
}

__device__ __forceinline__ float fexp2(float x) {
  float r;
  asm("v_exp_f32 %0, %1" : "=v"(r) : "v"(x));
  return r;
}

__device__ __forceinline__ float xmax32(float x) { return fmaxf(x, __shfl_xor(x, 32)); }
__device__ __forceinline__ float xsum32(float x) { return x + __shfl_xor(x, 32); }

__device__ __forceinline__ void gl_lds16(const unsigned short* g, unsigned short* l) {
  __builtin_amdgcn_global_load_lds((const __attribute__((address_space(1))) void*)g,
                                   (__attribute__((address_space(3))) void*)l, 16, 0, 0);
}

// ---- merged prep: wt (0..2303) | bias (2304..2495) | maskadd (2496..2497)
// (conv pass deleted: qkv converts fp32 A during staging)
__global__ __launch_bounds__(256) void k_prep(const float* __restrict__ Wq,
                                              const float* __restrict__ Wk,
                                              const float* __restrict__ Wv,
                                              const float* __restrict__ Wo,
                                              const float* __restrict__ rel_emb,
                                              const int* __restrict__ mask,
                                              unsigned short* __restrict__ Wq_t,
                                              unsigned short* __restrict__ Wk_t,
                                              unsigned short* __restrict__ Wv_t,
                                              unsigned short* __restrict__ Wo_t,
                                              float* __restrict__ bias_tab,
                                              float* __restrict__ maskadd,
                                              int* __restrict__ maskall) {
  __shared__ float shbuf[32 * 33];
  int blk = blockIdx.x, tid = threadIdx.x;
  if (blk < 2304) {
    int z = blk / 576, r2 = blk - z * 576;
    int bx = (r2 % 24) * 32, by = (r2 / 24) * 32;
    const float* w = (z == 0) ? Wq : (z == 1) ? Wk : (z == 2) ? Wv : Wo;
    unsigned short* o = (z == 0) ? Wq_t : (z == 1) ? Wk_t : (z == 2) ? Wv_t : Wo_t;
    float scale = (z == 0) ? 0.125f * LOG2E : 1.0f;
    int tx = tid & 31, ty = tid >> 5;
    float (*t)[33] = (float(*)[33])shbuf;
    for (int r = 0; r < 32; r += 8)
      t[ty + r][tx] = w[(by + ty + r) * ND + bx + tx];
    __syncthreads();
    for (int r = 0; r < 32; r += 8)
      o[(bx + ty + r) * ND + by + tx] = f2bf(t[tx][ty + r] * scale);
  } else if (blk < 2496) {
    int idx = (blk - 2304) * 256 + tid;
    if (idx >= 4095 * NH) return;
    int h = idx % NH;
    int di = idx / NH;
    int rel = di - 2047;          // rel = k - q
    int n = -rel;
    int ret = 0;
    if (n < 0) { ret = 16; n = -n; }
    int b;
    if (n < 8) {
      b = ret + n;
    } else {
      int v = (n >= 91) ? 7 : (n >= 64) ? 6 : (n >= 46) ? 5 : (n >= 32) ? 4
            : (n >= 23) ? 3 : (n >= 16) ? 2 : (n >= 12) ? 1 : 0;
      b = ret + 8 + v;
    }
    bias_tab[h * 4095 + di] = rel_emb[b * NH + h] * LOG2E;
  } else {
    int b = blk - 2496;
    int* red = (int*)shbuf;
    int acc = 1;
    for (int i = tid; i < NL; i += 256) {
      int m = mask[b * NL + i];
      maskadd[b * NL + i] = m ? 0.0f : -1e30f;
      acc &= (m != 0) ? 1 : 0;
    }
    red[tid] = acc;
    __syncthreads();
    for (int s2 = 128; s2 > 0; s2 >>= 1) {
      if (tid < s2) red[tid] &= red[tid + s2];
      __syncthreads();
    }
    if (tid == 0) maskall[b] = red[0];
  }
}

// ---- fused QKV GEMM, 128x96 tile, flat grid 768 with XCD swizzle. A is read
// DIRECTLY from the fp32 inputs: reg-staged float4 loads -> f2bf -> swizzled
// ds_write_b128 (manual writes allow the XOR swizzle; identical rounding to the
// deleted conv pass). B (weights, bf16) stays on gl_lds.
__global__ __launch_bounds__(256) void k_gemm_qkv(const float* __restrict__ qf,
                                                  const float* __restrict__ kvf,
                                                  const unsigned short* __restrict__ Wt,
                                                  unsigned short* __restrict__ Qb,
                                                  unsigned short* __restrict__ Kb,
                                                  unsigned short* __restrict__ Vt) {
  __shared__ unsigned short S[14336];   // A: [0,8192) 16KB, B: [8192,14336) 12KB
  unsigned short* As = S;
  unsigned short* Bs = S + 8192;
  int flat = blockIdx.x;
  int nf = (flat & 7) * 96 + (flat >> 3);   // bijective: 768 = 8*96
  int px = nf / 24;                          // A-panel index (0..31)
  int y  = nf - px * 24;                     // weight column (0..23)
  int tid = threadIdx.x;
  int wave = tid >> 6, lane = tid & 63;
  int lr = lane & 15, lg = lane >> 4;
  int m0 = px * 128;
  int z = y >> 3;                  // 0=Q, 1=K, 2=V
  int nc0 = (y & 7) * 96;          // col within the 768-wide section
  const float* A32 = (z == 0) ? qf : kvf;
  const unsigned short* Bt = Wt + (size_t)y * 96 * ND;
  int wm = (wave >> 1) * 64, wn = (wave & 1) * 48;
  int srow = tid >> 3, spc = tid & 7;
  int sg = spc ^ (srow & 7);
  const float* Agf = A32 + (size_t)(m0 + srow) * ND + sg * 8;
  const unsigned short* Bg = Bt + (size_t)srow * ND + sg * 8;
  f32x4 acc[4][3] = {};
  for (int t = 0; t < ND / 64; ++t) {
    int k0 = t * 64;
    // stage B first (async, in flight during A conversion)
#pragma unroll
    for (int s = 0; s < 3; ++s)
      gl_lds16(Bg + (size_t)(s * 32) * ND + k0, &Bs[s * 2048 + tid * 8]);
    // stage A: fp32 -> bf16, swizzled ds_write (LDS[row][spc] holds global chunk sg)
#pragma unroll
    for (int s = 0; s < 4; ++s) {
      const float4* p = (const float4*)(Agf + (size_t)(s * 32) * ND + k0);
      float4 a0 = p[0], a1 = p[1];
      ushort4 u0, u1;
      u0.x = f2bf(a0.x); u0.y = f2bf(a0.y); u0.z = f2bf(a0.z); u0.w = f2bf(a0.w);
      u1.x = f2bf(a1.x); u1.y = f2bf(a1.y); u1.z = f2bf(a1.z); u1.w = f2bf(a1.w);
      int rl = s * 32 + srow;
      *(ushort4*)&As[rl * 64 + spc * 8]     = u0;
      *(ushort4*)&As[rl * 64 + spc * 8 + 4] = u1;
    }
    __syncthreads();
#pragma unroll
    for (int ks = 0; ks < 2; ++ks) {
      bf16x8 af[4], bfr[3];
#pragma unroll
      for (int i = 0; i < 4; ++i) {
        int ar = wm + i * 16 + lr;
        af[i] = *(const bf16x8*)&As[ar * 64 + (((ks * 4 + lg) ^ (ar & 7)) * 8)];
      }
#pragma unroll
      for (int i = 0; i < 3; ++i) {
        int br = wn + i * 16 + lr;
        bfr[i] = *(const bf16x8*)&Bs[br * 64 + (((ks * 4 + lg) ^ (br & 7)) * 8)];
      }
#pragma unroll
      for (int mi = 0; mi < 4; ++mi)
#pragma unroll
        for (int ni = 0; ni < 3; ++ni)
          acc[mi][ni] = __builtin_amdgcn_mfma_f32_16x16x32_bf16(af[mi], bfr[ni], acc[mi][ni], 0, 0, 0);
    }
    __syncthreads();
  }
  if (z == 2) {
    // transpose through LDS: T[col][row], chunk-XOR swizzle (chunk ^= col&7)
    unsigned short* T = S;
#pragma unroll
    for (int mi = 0; mi < 4; ++mi)
#pragma unroll
      for (int ni = 0; ni < 3; ++ni) {
        int col  = wn + ni * 16 + lr;      // dk within tile, 0..95
        int rowb = wm + mi * 16 + lg * 4;  // l within tile, 4 consecutive rows
        ushort4 v4;
        v4.x = f2bf(acc[mi][ni][0]);
        v4.y = f2bf(acc[mi][ni][1]);
        v4.z = f2bf(acc[mi][ni][2]);
        v4.w = f2bf(acc[mi][ni][3]);
        int addr = col * 128 + (((rowb >> 3) ^ (col & 7)) * 8) + (rowb & 7);
        *(ushort4*)&T[addr] = v4;          // 8B aligned: (rowb&7) in {0,4}
      }
    __syncthreads();
    int bb = m0 >> 11;
    unsigned short* vdst = Vt + (((size_t)bb * ND + nc0) << 11) + (m0 & 2047);
#pragma unroll
    for (int pass = 0; pass < 6; ++pass) {
      int col = (tid >> 4) + pass * 16;    // 16 cols per pass, 96 total
      int cc = tid & 15;                   // 16 chunks of 8 elems per col
      u32x4 val = *(const u32x4*)&T[col * 128 + ((cc ^ (col & 7)) * 8)];
      *(u32x4*)&vdst[((size_t)col << 11) + cc * 8] = val;  // 256B/16 lanes contiguous
    }
  } else {
#pragma unroll
    for (int mi = 0; mi < 4; ++mi)
#pragma unroll
      for (int ni = 0; ni < 3; ++ni)
#pragma unroll
        for (int r = 0; r < 4; ++r) {
          int row = m0 + wm + mi * 16 + lg * 4 + r;
          int col = nc0 + wn + ni * 16 + lr;
          unsigned short v = f2bf(acc[mi][ni][r]);
          if (z == 0) Qb[(size_t)row * ND + col] = v;
          else        Kb[(size_t)row * ND + col] = v;
        }
  }
}

// ---- out-proj GEMM: C[M,N] fp32 = A[M,K] bf16 * Bt[N,K]^T. 64x64 tile, flat grid
// 768 + XCD swizzle + dbuf LDS with prefetch-before-compute.
__global__ __launch_bounds__(256) void k_gemm(const unsigned short* __restrict__ A,
                                              const unsigned short* __restrict__ Bt,
                                              float* __restrict__ Cout,
                                              int Msz, int Nsz, int Ksz) {
  __shared__ unsigned short As[2][4096];   // [64][64] per buf
  __shared__ unsigned short Bs[2][4096];
  int flat = blockIdx.x;
  int nf = (flat & 7) * 96 + (flat >> 3);   // bijective: 768 = 8*96
  int px = nf / 12;                          // A-panel (0..63)
  int y  = nf - px * 12;                     // N-column (0..11)
  int tid = threadIdx.x;
  int wave = tid >> 6, lane = tid & 63;
  int lr = lane & 15, lg = lane >> 4;
  int m0 = px * 64, n0 = y * 64;
  int wm = (wave >> 1) * 32, wn = (wave & 1) * 32;
  int srow = tid >> 3, spc = tid & 7;
  int sg = spc ^ (srow & 7);
  const unsigned short* Ag = A  + (size_t)(m0 + srow) * Ksz + sg * 8;
  const unsigned short* Bg = Bt + (size_t)(n0 + srow) * Ksz + sg * 8;
  f32x4 acc[2][2] = {};
  const int KT = Ksz >> 6;
#pragma unroll
  for (int s = 0; s < 2; ++s) {
    gl_lds16(Ag + (size_t)(s * 32) * Ksz, &As[0][s * 2048 + tid * 8]);
    gl_lds16(Bg + (size_t)(s * 32) * Ksz, &Bs[0][s * 2048 + tid * 8]);
  }
  __syncthreads();
  int cur = 0;
  for (int t = 0; t < KT; ++t) {
    if (t + 1 < KT) {
      int k0 = (t + 1) << 6;
#pragma unroll
      for (int s = 0; s < 2; ++s) {
        gl_lds16(Ag + (size_t)(s * 32) * Ksz + k0, &As[cur ^ 1][s * 2048 + tid * 8]);
        gl_lds16(Bg + (size_t)(s * 32) * Ksz + k0, &Bs[cur ^ 1][s * 2048 + tid * 8]);
      }
    }
#pragma unroll
    for (int ks = 0; ks < 2; ++ks) {
      bf16x8 af[2], bfr[2];
#pragma unroll
      for (int i = 0; i < 2; ++i) {
        int ar = wm + i * 16 + lr;
        af[i] = *(const bf16x8*)&As[cur][ar * 64 + (((ks * 4 + lg) ^ (ar & 7)) * 8)];
        int br = wn + i * 16 + lr;
        bfr[i] = *(const bf16x8*)&Bs[cur][br * 64 + (((ks * 4 + lg) ^ (br & 7)) * 8)];
      }
#pragma unroll
      for (int mi = 0; mi < 2; ++mi)
#pragma unroll
        for (int ni = 0; ni < 2; ++ni)
          acc[mi][ni] = __builtin_amdgcn_mfma_f32_16x16x32_bf16(af[mi], bfr[ni], acc[mi][ni], 0, 0, 0);
    }
    __syncthreads();
    cur ^= 1;
  }
#pragma unroll
  for (int mi = 0; mi < 2; ++mi)
#pragma unroll
    for (int ni = 0; ni < 2; ++ni)
#pragma unroll
      for (int r = 0; r < 4; ++r) {
        int row = m0 + wm + mi * 16 + lg * 4 + r;
        int col = n0 + wn + ni * 16 + lr;
        Cout[(size_t)row * Nsz + col] = acc[mi][ni][r];
      }
}

// ---- fused flash attention (R15 structure, unchanged except max3-grouped tree)
__global__ __launch_bounds__(256, 3) void k_attn(const unsigned short* __restrict__ Qb,
                                                 const unsigned short* __restrict__ Kb,
                                                 const unsigned short* __restrict__ Vt,
                                                 const float* __restrict__ bias_tab,
                                                 const float* __restrict__ maskadd,
                                                 const int* __restrict__ maskall,
                                                 unsigned short* __restrict__ Ob) {
  __shared__ unsigned short Ks[3][4096];   // [64 phys keys][64 dk], XOR-swizzled chunks
  __shared__ unsigned short Vs[3][4096];   // [64 dk][64 keys natural], XOR-swizzled
  __shared__ float biasw[384];             // near band: biasw[d+191]
  int flat = blockIdx.x;
  int nf = (flat & 7) * 96 + (flat >> 3);
  int qt = nf & 31, bh = nf >> 5;
  int b = bh / NH, h = bh % NH;
  int tid = threadIdx.x, wave = tid >> 6, lane = tid & 63;
  int lr = lane & 15, lg = lane >> 4;
  int q0 = qt * 64;
  for (int i = tid; i < 383; i += 256) biasw[i] = bias_tab[h * 4095 + 1856 + i];
  float cFlo = bias_tab[h * 4095];          // d <= -91 saturated (bucket 15)
  float cFhi = bias_tab[h * 4095 + 4094];   // d >= +91 saturated (bucket 31)
  const unsigned short* Kbase = Kb + (size_t)(b * NL) * ND + h * NDK;
  const unsigned short* Vbase = Vt + (size_t)(b * NH + h) * NDK * NL;
  int srow = tid >> 3, spc = tid & 7;
  int sg = spc ^ (srow & 7);
  // key permutation: phys row srow stores logical key l0; +32 phys -> l0+4
  int l0 = (srow >> 4) * 32 + ((srow >> 2) & 3) * 8 + (srow & 3);
  const unsigned short* Kg0 = Kbase + (size_t)l0 * ND + sg * 8;
  const unsigned short* Kg1 = Kbase + (size_t)(l0 + 4) * ND + sg * 8;
  const unsigned short* Vg0 = Vbase + (size_t)srow * NL + sg * 8;
  const unsigned short* Vg1 = Vbase + (size_t)(32 + srow) * NL + sg * 8;
  bf16x8 aq[2];
  int qw = q0 + wave * 16;
#pragma unroll
  for (int ks = 0; ks < 2; ++ks)
    aq[ks] = *(const bf16x8*)&Qb[(size_t)(b * NL + qw + lr) * ND + h * NDK + ks * 32 + lg * 8];
  const float* cbase = maskadd + b * NL;
  int nomask = __builtin_amdgcn_readfirstlane(maskall[b]);
  f32x4 accO[4] = {};
  float mst = -1e30f, lstl = 0.f;          // per-lane partial row-sum (16 keys/lane)
  int bconst = lg * 8 - wave * 16 - lr + 191 - q0;
  int src0 = (lane & 48) | ((lane >> 2) & 12);
  // prologue: stage tiles 0 and 1 into bufs 0, 1 (8 loads in flight)
  gl_lds16(Kg0, &Ks[0][tid * 8]);
  gl_lds16(Kg1, &Ks[0][2048 + tid * 8]);
  gl_lds16(Vg0, &Vs[0][tid * 8]);
  gl_lds16(Vg1, &Vs[0][2048 + tid * 8]);
  {
    size_t kok = (size_t)64 * ND, kov = 64;
    gl_lds16(Kg0 + kok, &Ks[1][tid * 8]);
    gl_lds16(Kg1 + kok, &Ks[1][2048 + tid * 8]);
    gl_lds16(Vg0 + kov, &Vs[1][tid * 8]);
    gl_lds16(Vg1 + kov, &Vs[1][2048 + tid * 8]);
  }
  asm volatile("s_waitcnt vmcnt(4) lgkmcnt(0)" ::: "memory");  // tile0 + biasw ready
  __builtin_amdgcn_s_barrier();
  // stage pointers for tile 2 onward (advance by constant stride per stage)
  const unsigned short* sk0 = Kg0 + (size_t)2 * 64 * ND;
  const unsigned short* sk1 = Kg1 + (size_t)2 * 64 * ND;
  const unsigned short* sv0 = Vg0 + 2 * 64;
  const unsigned short* sv1 = Vg1 + 2 * 64;

  auto body = [&](int kt_, auto CURc, auto PFc) {
    constexpr int CUR = decltype(CURc)::v;
    constexpr int PF  = decltype(PFc)::v;
    constexpr int ST  = (CUR + 2) % 3;
    float4 cv[2][2];
    if (!nomask) {
#pragma unroll
      for (int hf = 0; hf < 2; ++hf)
#pragma unroll
        for (int qd = 0; qd < 2; ++qd)
          cv[hf][qd] = *(const float4*)&cbase[kt_ * 64 + hf * 32 + lg * 8 + qd * 4];
    }
    if (PF) {
      gl_lds16(sk0, &Ks[ST][tid * 8]);
      gl_lds16(sk1, &Ks[ST][2048 + tid * 8]);
      gl_lds16(sv0, &Vs[ST][tid * 8]);
      gl_lds16(sv1, &Vs[ST][2048 + tid * 8]);
      sk0 += 64 * ND; sk1 += 64 * ND; sv0 += 64; sv1 += 64;
    }
    int kt64 = kt_ * 64;
    bool farlo = (kt64 + 63 < q0 - 90), farhi = (kt64 > q0 + 153);
    float ctile = farlo ? cFlo : (farhi ? cFhi : 0.0f);
    f32x4 s[4];
    __builtin_amdgcn_s_setprio(1);
    if (nomask && (farlo || farhi)) {
      const f32x4 z = {0.f, 0.f, 0.f, 0.f};
#pragma unroll
      for (int ni = 0; ni < 4; ++ni) {
        int kr = ni * 16 + lr;
        bf16x8 bk0 = *(const bf16x8*)&Ks[CUR][kr * 64 + ((lg ^ (lr & 7)) * 8)];
        bf16x8 bk1 = *(const bf16x8*)&Ks[CUR][kr * 64 + (((4 + lg) ^ (lr & 7)) * 8)];
        s[ni] = __builtin_amdgcn_mfma_f32_16x16x32_bf16(bk0, aq[0], z, 0, 0, 0);
        s[ni] = __builtin_amdgcn_mfma_f32_16x16x32_bf16(bk1, aq[1], s[ni], 0, 0, 0);
      }
    } else {
      if (farlo || farhi) {
#pragma unroll
        for (int ni = 0; ni < 4; ++ni)
#pragma unroll
          for (int r = 0; r < 4; ++r) s[ni][r] = 0.f;   // ctile folded later
      } else {
#pragma unroll
        for (int ni = 0; ni < 4; ++ni)
#pragma unroll
          for (int r = 0; r < 4; ++r)
            s[ni][r] = biasw[kt64 + (ni & 1) * 32 + (ni >> 1) * 4 + r + bconst];
      }
      if (!nomask) {
#pragma unroll
        for (int ni = 0; ni < 4; ++ni)
#pragma unroll
          for (int r = 0; r < 4; ++r)
            s[ni][r] += ((const float*)&cv[ni & 1][ni >> 1])[r];
      }
#pragma unroll
      for (int ni = 0; ni < 4; ++ni) {
        int kr = ni * 16 + lr;
        bf16x8 bk0 = *(const bf16x8*)&Ks[CUR][kr * 64 + ((lg ^ (lr & 7)) * 8)];
        bf16x8 bk1 = *(const bf16x8*)&Ks[CUR][kr * 64 + (((4 + lg) ^ (lr & 7)) * 8)];
        s[ni] = __builtin_amdgcn_mfma_f32_16x16x32_bf16(bk0, aq[0], s[ni], 0, 0, 0);
        s[ni] = __builtin_amdgcn_mfma_f32_16x16x32_bf16(bk1, aq[1], s[ni], 0, 0, 0);
      }
    }
    __builtin_amdgcn_s_setprio(0);
    // lane-local max: max3-fusable triple groupings (16 values, 8 ops, depth 3)
    float a0 = fmaxf(fmaxf(s[0][0], s[0][1]), s[0][2]);
    float a1 = fmaxf(fmaxf(s[0][3], s[1][0]), s[1][1]);
    float a2 = fmaxf(fmaxf(s[1][2], s[1][3]), s[2][0]);
    float a3 = fmaxf(fmaxf(s[2][1], s[2][2]), s[2][3]);
    float a4 = fmaxf(fmaxf(s[3][0], s[3][1]), s[3][2]);
    float lm = fmaxf(fmaxf(fmaxf(a0, a1), a2), fmaxf(fmaxf(a3, a4), s[3][3]));
    if (!__all(lm + ctile - mst <= 8.0f)) {
      float pmax = fmaxf(lm, __shfl_xor(lm, 16));
      pmax = xmax32(pmax);
      float pm2 = pmax + ctile;
      float mnew = fmaxf(mst, pm2);
      float sc = fexp2(mst - mnew);
      float scB[4];
#pragma unroll
      for (int r = 0; r < 4; ++r) scB[r] = __shfl(sc, src0 | r);
#pragma unroll
      for (int ni = 0; ni < 4; ++ni)
#pragma unroll
        for (int r = 0; r < 4; ++r) accO[ni][r] *= scB[r];
      lstl *= sc;
      mst = mnew;
    }
    float msub = mst - ctile;
#pragma unroll
    for (int ni = 0; ni < 4; ++ni)
#pragma unroll
      for (int r = 0; r < 4; ++r) s[ni][r] = fexp2(s[ni][r] - msub);
    {
      f32x4 ta = s[0] + s[1];
      f32x4 tb = s[2] + s[3];
      ta = ta + tb;
      lstl += (ta[0] + ta[1]) + (ta[2] + ta[3]);
    }
    // pack P: lane's 16 values are exactly its PV A-fragments (key permutation)
    unsigned pw[8];
#pragma unroll
    for (int ni = 0; ni < 4; ++ni) {
      unsigned a, c;
      asm("v_cvt_pk_bf16_f32 %0, %1, %2" : "=v"(a) : "v"(s[ni][0]), "v"(s[ni][1]));
      asm("v_cvt_pk_bf16_f32 %0, %1, %2" : "=v"(c) : "v"(s[ni][2]), "v"(s[ni][3]));
      pw[ni * 2] = a; pw[ni * 2 + 1] = c;
    }
    u32x4 apw0 = {pw[0], pw[1], pw[4], pw[5]};
    u32x4 apw1 = {pw[2], pw[3], pw[6], pw[7]};
    bf16x8 ap0 = __builtin_bit_cast(bf16x8, apw0);
    bf16x8 ap1 = __builtin_bit_cast(bf16x8, apw1);
    // O += P @ V
    __builtin_amdgcn_s_setprio(1);
#pragma unroll
    for (int ni = 0; ni < 4; ++ni) {
      int vr = ni * 16 + lr;
      bf16x8 bv0 = *(const bf16x8*)&Vs[CUR][vr * 64 + ((lg ^ (lr & 7)) * 8)];
      bf16x8 bv1 = *(const bf16x8*)&Vs[CUR][vr * 64 + (((4 + lg) ^ (lr & 7)) * 8)];
      accO[ni] = __builtin_amdgcn_mfma_f32_16x16x32_bf16(ap0, bv0, accO[ni], 0, 0, 0);
      accO[ni] = __builtin_amdgcn_mfma_f32_16x16x32_bf16(ap1, bv1, accO[ni], 0, 0, 0);
    }
    __builtin_amdgcn_s_setprio(0);
    if (PF) asm volatile("s_waitcnt vmcnt(4)" ::: "memory");
    else    asm volatile("s_waitcnt vmcnt(0)" ::: "memory");
    __builtin_amdgcn_s_barrier();
  };

  for (int kt = 0; kt < 30; kt += 3) {   // tile kt uses buf kt%3; stages kt+2
    body(kt,     IC<0>{}, IC<1>{});
    body(kt + 1, IC<1>{}, IC<1>{});
    body(kt + 2, IC<2>{}, IC<1>{});
  }
  body(30, IC<0>{}, IC<0>{});
  body(31, IC<1>{}, IC<0>{});

  // epilogue: one cross-lane row-sum, then broadcast 1/l to accO's row layout
  float lst = lstl + __shfl_xor(lstl, 16);
  lst = xsum32(lst);
  float linv = 1.0f / lst;
  float lB[4];
#pragma unroll
  for (int r = 0; r < 4; ++r) lB[r] = __shfl(linv, src0 | r);
#pragma unroll
  for (int ni = 0; ni < 4; ++ni)
#pragma unroll
    for (int r = 0; r < 4; ++r) {
      int qg = qw + lg * 4 + r;
      int col = h * NDK + ni * 16 + lr;
      Ob[(size_t)(b * NL + qg) * ND + col] = f2bf(accO[ni][r] * lB[r]);
    }
}

extern "C" void kernel_launch(void* const* d_in, const int* in_sizes, int n_in,
                              void* d_out, int out_size, void* d_ws, size_t ws_size,
                              hipStream_t stream) {
  const float* query  = (const float*)d_in[0];
  const float* keyval = (const float*)d_in[1];
  const int*   mask   = (const int*)d_in[2];
  const float* Wq     = (const float*)d_in[3];
  const float* Wk     = (const float*)d_in[4];
  const float* Wv     = (const float*)d_in[5];
  const float* Wo     = (const float*)d_in[6];
  const float* rel    = (const float*)d_in[7];

  char* ws = (char*)d_ws;
  unsigned short* Wq_t  = (unsigned short*)(ws + 12582912);   // [N][K] bf16 (x 0.125*log2e)
  unsigned short* Wk_t  = (unsigned short*)(ws + 13762560);
  unsigned short* Wv_t  = (unsigned short*)(ws + 14942208);
  unsigned short* Wo_t  = (unsigned short*)(ws + 16121856);
  unsigned short* Qb    = (unsigned short*)(ws + 17301504);   // [B,L,H,DK]
  unsigned short* Kb    = (unsigned short*)(ws + 23592960);
  unsigned short* Vt    = (unsigned short*)(ws + 29884416);   // [B,768,L]
  unsigned short* Ob    = (unsigned short*)(ws + 36175872);   // [B,L,H*DK]
  float* bias_tab       = (float*)(ws + 42467328);            // [H][4095], x log2e
  float* maskadd        = (float*)(ws + 42663936);            // [B][L]
  int*   maskall        = (int*)(ws + 42680320);              // [B]

  k_prep<<<dim3(2498), dim3(256), 0, stream>>>(Wq, Wk, Wv, Wo, rel, mask,
                                               Wq_t, Wk_t, Wv_t, Wo_t,
                                               bias_tab, maskadd, maskall);
  k_gemm_qkv<<<dim3(768), dim3(256), 0, stream>>>(query, keyval, Wq_t, Qb, Kb, Vt);
  k_attn<<<dim3(768), dim3(256), 0, stream>>>(Qb, Kb, Vt, bias_tab, maskadd, maskall, Ob);
  k_gemm<<<dim3(768), dim3(256), 0, stream>>>(Ob, Wo_t, (float*)d_out, NM, ND, ND);
}

// Round 18
// 91.850 us; speedup vs baseline: 1.0748x; 1.0748x over previous
//
#include <hip/hip_runtime.h>
#include <stdint.h>

typedef __attribute__((ext_vector_type(8))) short bf16x8;
typedef __attribute__((ext_vector_type(4))) float f32x4;
typedef __attribute__((ext_vector_type(4))) unsigned int u32x4;

#define NB 2
#define NL 2048
#define ND 768
#define NH 12
#define NDK 64
#define NM 4096   // NB*NL
#define LOG2E 1.4426950408889634f

template<int N> struct IC { static constexpr int v = N; };

__device__ __forceinline__ unsigned short f2bf(float f) {
  unsigned u = __builtin_bit_cast(unsigned, f);
  u += 0x7FFFu + ((u >> 16) & 1u);          // RNE
  return (unsigned short)(u >> 16);
}

__device__ __forceinline__ float fexp2(float x) {
  float r;
  asm("v_exp_f32 %0, %1" : "=v"(r) : "v"(x));
  return r;
}

__device__ __forceinline__ float xmax32(float x) { return fmaxf(x, __shfl_xor(x, 32)); }
__device__ __forceinline__ float xsum32(float x) { return x + __shfl_xor(x, 32); }

__device__ __forceinline__ void gl_lds16(const unsigned short* g, unsigned short* l) {
  __builtin_amdgcn_global_load_lds((const __attribute__((address_space(1))) void*)g,
                                   (__attribute__((address_space(3))) void*)l, 16, 0, 0);
}

// ---- merged prep: conv (0..6143) | wt (6144..8447) | bias (8448..8639) | maskadd (8640..8641)
__global__ __launch_bounds__(256) void k_prep(const float* __restrict__ query,
                                              const float* __restrict__ keyval,
                                              const float* __restrict__ Wq,
                                              const float* __restrict__ Wk,
                                              const float* __restrict__ Wv,
                                              const float* __restrict__ Wo,
                                              const float* __restrict__ rel_emb,
                                              const int* __restrict__ mask,
                                              unsigned short* __restrict__ q_bf,
                                              unsigned short* __restrict__ kv_bf,
                                              unsigned short* __restrict__ Wq_t,
                                              unsigned short* __restrict__ Wk_t,
                                              unsigned short* __restrict__ Wv_t,
                                              unsigned short* __restrict__ Wo_t,
                                              float* __restrict__ bias_tab,
                                              float* __restrict__ maskadd,
                                              int* __restrict__ maskall) {
  __shared__ float shbuf[32 * 33];
  int blk = blockIdx.x, tid = threadIdx.x;
  if (blk < 6144) {
    int y = blk / 3072;
    int i = (blk - y * 3072) * 256 + tid;
    const float* src = y ? keyval : query;
    unsigned short* dst = y ? kv_bf : q_bf;
    float4 v = ((const float4*)src)[i];
    ushort4 o;
    o.x = f2bf(v.x); o.y = f2bf(v.y); o.z = f2bf(v.z); o.w = f2bf(v.w);
    ((ushort4*)dst)[i] = o;
  } else if (blk < 8448) {
    int rel = blk - 6144;
    int z = rel / 576, r2 = rel - z * 576;
    int bx = (r2 % 24) * 32, by = (r2 / 24) * 32;
    const float* w = (z == 0) ? Wq : (z == 1) ? Wk : (z == 2) ? Wv : Wo;
    unsigned short* o = (z == 0) ? Wq_t : (z == 1) ? Wk_t : (z == 2) ? Wv_t : Wo_t;
    float scale = (z == 0) ? 0.125f * LOG2E : 1.0f;
    int tx = tid & 31, ty = tid >> 5;
    float (*t)[33] = (float(*)[33])shbuf;
    for (int r = 0; r < 32; r += 8)
      t[ty + r][tx] = w[(by + ty + r) * ND + bx + tx];
    __syncthreads();
    for (int r = 0; r < 32; r += 8)
      o[(bx + ty + r) * ND + by + tx] = f2bf(t[tx][ty + r] * scale);
  } else if (blk < 8640) {
    int idx = (blk - 8448) * 256 + tid;
    if (idx >= 4095 * NH) return;
    int h = idx % NH;
    int di = idx / NH;
    int rel = di - 2047;          // rel = k - q
    int n = -rel;
    int ret = 0;
    if (n < 0) { ret = 16; n = -n; }
    int b;
    if (n < 8) {
      b = ret + n;
    } else {
      int v = (n >= 91) ? 7 : (n >= 64) ? 6 : (n >= 46) ? 5 : (n >= 32) ? 4
            : (n >= 23) ? 3 : (n >= 16) ? 2 : (n >= 12) ? 1 : 0;
      b = ret + 8 + v;
    }
    bias_tab[h * 4095 + di] = rel_emb[b * NH + h] * LOG2E;
  } else {
    int b = blk - 8640;
    int* red = (int*)shbuf;
    int acc = 1;
    for (int i = tid; i < NL; i += 256) {
      int m = mask[b * NL + i];
      maskadd[b * NL + i] = m ? 0.0f : -1e30f;
      acc &= (m != 0) ? 1 : 0;
    }
    red[tid] = acc;
    __syncthreads();
    for (int s2 = 128; s2 > 0; s2 >>= 1) {
      if (tid < s2) red[tid] &= red[tid + s2];
      __syncthreads();
    }
    if (tid == 0) maskall[b] = red[0];
  }
}

// ---- fused QKV GEMM, 128x96 tile, grid (32,24) = 768 = 3/CU (R16 proven form).
// bf16 A via gl_lds; V blocks transpose through LDS for coalesced Vt stores.
__global__ __launch_bounds__(256) void k_gemm_qkv(const unsigned short* __restrict__ q_bf,
                                                  const unsigned short* __restrict__ kv_bf,
                                                  const unsigned short* __restrict__ Wt,
                                                  unsigned short* __restrict__ Qb,
                                                  unsigned short* __restrict__ Kb,
                                                  unsigned short* __restrict__ Vt) {
  __shared__ unsigned short S[14336];   // A: [0,8192) 16KB, B: [8192,14336) 12KB
  unsigned short* As = S;
  unsigned short* Bs = S + 8192;
  int tid = threadIdx.x;
  int wave = tid >> 6, lane = tid & 63;
  int lr = lane & 15, lg = lane >> 4;
  int m0 = blockIdx.x * 128;
  int z = blockIdx.y >> 3;                 // 0=Q, 1=K, 2=V
  int nc0 = (blockIdx.y & 7) * 96;         // col within the 768-wide section
  const unsigned short* A  = (z == 0) ? q_bf : kv_bf;
  const unsigned short* Bt = Wt + (size_t)blockIdx.y * 96 * ND;
  int wm = (wave >> 1) * 64, wn = (wave & 1) * 48;
  int srow = tid >> 3, spc = tid & 7;
  int sg = spc ^ (srow & 7);
  const unsigned short* Ag = A  + (size_t)(m0 + srow) * ND + sg * 8;
  const unsigned short* Bg = Bt + (size_t)srow * ND + sg * 8;
  f32x4 acc[4][3] = {};
  for (int t = 0; t < ND / 64; ++t) {
    int k0 = t * 64;
#pragma unroll
    for (int s = 0; s < 4; ++s)
      gl_lds16(Ag + (size_t)(s * 32) * ND + k0, &As[s * 2048 + tid * 8]);
#pragma unroll
    for (int s = 0; s < 3; ++s)
      gl_lds16(Bg + (size_t)(s * 32) * ND + k0, &Bs[s * 2048 + tid * 8]);
    __syncthreads();
#pragma unroll
    for (int ks = 0; ks < 2; ++ks) {
      bf16x8 af[4], bfr[3];
#pragma unroll
      for (int i = 0; i < 4; ++i) {
        int ar = wm + i * 16 + lr;
        af[i] = *(const bf16x8*)&As[ar * 64 + (((ks * 4 + lg) ^ (ar & 7)) * 8)];
      }
#pragma unroll
      for (int i = 0; i < 3; ++i) {
        int br = wn + i * 16 + lr;
        bfr[i] = *(const bf16x8*)&Bs[br * 64 + (((ks * 4 + lg) ^ (br & 7)) * 8)];
      }
#pragma unroll
      for (int mi = 0; mi < 4; ++mi)
#pragma unroll
        for (int ni = 0; ni < 3; ++ni)
          acc[mi][ni] = __builtin_amdgcn_mfma_f32_16x16x32_bf16(af[mi], bfr[ni], acc[mi][ni], 0, 0, 0);
    }
    __syncthreads();
  }
  if (z == 2) {
    // transpose through LDS: T[col][row], chunk-XOR swizzle (chunk ^= col&7)
    unsigned short* T = S;
#pragma unroll
    for (int mi = 0; mi < 4; ++mi)
#pragma unroll
      for (int ni = 0; ni < 3; ++ni) {
        int col  = wn + ni * 16 + lr;      // dk within tile, 0..95
        int rowb = wm + mi * 16 + lg * 4;  // l within tile, 4 consecutive rows
        ushort4 v4;
        v4.x = f2bf(acc[mi][ni][0]);
        v4.y = f2bf(acc[mi][ni][1]);
        v4.z = f2bf(acc[mi][ni][2]);
        v4.w = f2bf(acc[mi][ni][3]);
        int addr = col * 128 + (((rowb >> 3) ^ (col & 7)) * 8) + (rowb & 7);
        *(ushort4*)&T[addr] = v4;          // 8B aligned: (rowb&7) in {0,4}
      }
    __syncthreads();
    int bb = m0 >> 11;
    unsigned short* vdst = Vt + (((size_t)bb * ND + nc0) << 11) + (m0 & 2047);
#pragma unroll
    for (int pass = 0; pass < 6; ++pass) {
      int col = (tid >> 4) + pass * 16;    // 16 cols per pass, 96 total
      int cc = tid & 15;                   // 16 chunks of 8 elems per col
      u32x4 val = *(const u32x4*)&T[col * 128 + ((cc ^ (col & 7)) * 8)];
      *(u32x4*)&vdst[((size_t)col << 11) + cc * 8] = val;  // 256B/16 lanes contiguous
    }
  } else {
#pragma unroll
    for (int mi = 0; mi < 4; ++mi)
#pragma unroll
      for (int ni = 0; ni < 3; ++ni)
#pragma unroll
        for (int r = 0; r < 4; ++r) {
          int row = m0 + wm + mi * 16 + lg * 4 + r;
          int col = nc0 + wn + ni * 16 + lr;
          unsigned short v = f2bf(acc[mi][ni][r]);
          if (z == 0) Qb[(size_t)row * ND + col] = v;
          else        Kb[(size_t)row * ND + col] = v;
        }
  }
}

// ---- out-proj GEMM: C[M,N] fp32 = A[M,K] bf16 * Bt[N,K]^T. 64x64 tile, flat grid
// 768 + XCD swizzle + dbuf LDS with prefetch-before-compute.
__global__ __launch_bounds__(256) void k_gemm(const unsigned short* __restrict__ A,
                                              const unsigned short* __restrict__ Bt,
                                              float* __restrict__ Cout,
                                              int Msz, int Nsz, int Ksz) {
  __shared__ unsigned short As[2][4096];   // [64][64] per buf
  __shared__ unsigned short Bs[2][4096];
  int flat = blockIdx.x;
  int nf = (flat & 7) * 96 + (flat >> 3);   // bijective: 768 = 8*96
  int px = nf / 12;                          // A-panel (0..63)
  int y  = nf - px * 12;                     // N-column (0..11)
  int tid = threadIdx.x;
  int wave = tid >> 6, lane = tid & 63;
  int lr = lane & 15, lg = lane >> 4;
  int m0 = px * 64, n0 = y * 64;
  int wm = (wave >> 1) * 32, wn = (wave & 1) * 32;
  int srow = tid >> 3, spc = tid & 7;
  int sg = spc ^ (srow & 7);
  const unsigned short* Ag = A  + (size_t)(m0 + srow) * Ksz + sg * 8;
  const unsigned short* Bg = Bt + (size_t)(n0 + srow) * Ksz + sg * 8;
  f32x4 acc[2][2] = {};
  const int KT = Ksz >> 6;
#pragma unroll
  for (int s = 0; s < 2; ++s) {
    gl_lds16(Ag + (size_t)(s * 32) * Ksz, &As[0][s * 2048 + tid * 8]);
    gl_lds16(Bg + (size_t)(s * 32) * Ksz, &Bs[0][s * 2048 + tid * 8]);
  }
  __syncthreads();
  int cur = 0;
  for (int t = 0; t < KT; ++t) {
    if (t + 1 < KT) {
      int k0 = (t + 1) << 6;
#pragma unroll
      for (int s = 0; s < 2; ++s) {
        gl_lds16(Ag + (size_t)(s * 32) * Ksz + k0, &As[cur ^ 1][s * 2048 + tid * 8]);
        gl_lds16(Bg + (size_t)(s * 32) * Ksz + k0, &Bs[cur ^ 1][s * 2048 + tid * 8]);
      }
    }
#pragma unroll
    for (int ks = 0; ks < 2; ++ks) {
      bf16x8 af[2], bfr[2];
#pragma unroll
      for (int i = 0; i < 2; ++i) {
        int ar = wm + i * 16 + lr;
        af[i] = *(const bf16x8*)&As[cur][ar * 64 + (((ks * 4 + lg) ^ (ar & 7)) * 8)];
        int br = wn + i * 16 + lr;
        bfr[i] = *(const bf16x8*)&Bs[cur][br * 64 + (((ks * 4 + lg) ^ (br & 7)) * 8)];
      }
#pragma unroll
      for (int mi = 0; mi < 2; ++mi)
#pragma unroll
        for (int ni = 0; ni < 2; ++ni)
          acc[mi][ni] = __builtin_amdgcn_mfma_f32_16x16x32_bf16(af[mi], bfr[ni], acc[mi][ni], 0, 0, 0);
    }
    __syncthreads();
    cur ^= 1;
  }
#pragma unroll
  for (int mi = 0; mi < 2; ++mi)
#pragma unroll
    for (int ni = 0; ni < 2; ++ni)
#pragma unroll
      for (int r = 0; r < 4; ++r) {
        int row = m0 + wm + mi * 16 + lg * 4 + r;
        int col = n0 + wn + ni * 16 + lr;
        Cout[(size_t)row * Nsz + col] = acc[mi][ni][r];
      }
}

// ---- fused flash attention (R15 structure + max3-grouped tree): swapped-QK^T
// (exp2), 3-buffer counted-vmcnt pipeline, far-tile zero-C bias, lane-local
// softmax, XCD-aware block swizzle (FETCH 52->9 MB verified).
__global__ __launch_bounds__(256, 3) void k_attn(const unsigned short* __restrict__ Qb,
                                                 const unsigned short* __restrict__ Kb,
                                                 const unsigned short* __restrict__ Vt,
                                                 const float* __restrict__ bias_tab,
                                                 const float* __restrict__ maskadd,
                                                 const int* __restrict__ maskall,
                                                 unsigned short* __restrict__ Ob) {
  __shared__ unsigned short Ks[3][4096];   // [64 phys keys][64 dk], XOR-swizzled chunks
  __shared__ unsigned short Vs[3][4096];   // [64 dk][64 keys natural], XOR-swizzled
  __shared__ float biasw[384];             // near band: biasw[d+191]
  int flat = blockIdx.x;
  int nf = (flat & 7) * 96 + (flat >> 3);
  int qt = nf & 31, bh = nf >> 5;
  int b = bh / NH, h = bh % NH;
  int tid = threadIdx.x, wave = tid >> 6, lane = tid & 63;
  int lr = lane & 15, lg = lane >> 4;
  int q0 = qt * 64;
  for (int i = tid; i < 383; i += 256) biasw[i] = bias_tab[h * 4095 + 1856 + i];
  float cFlo = bias_tab[h * 4095];          // d <= -91 saturated (bucket 15)
  float cFhi = bias_tab[h * 4095 + 4094];   // d >= +91 saturated (bucket 31)
  const unsigned short* Kbase = Kb + (size_t)(b * NL) * ND + h * NDK;
  const unsigned short* Vbase = Vt + (size_t)(b * NH + h) * NDK * NL;
  int srow = tid >> 3, spc = tid & 7;
  int sg = spc ^ (srow & 7);
  // key permutation: phys row srow stores logical key l0; +32 phys -> l0+4
  int l0 = (srow >> 4) * 32 + ((srow >> 2) & 3) * 8 + (srow & 3);
  const unsigned short* Kg0 = Kbase + (size_t)l0 * ND + sg * 8;
  const unsigned short* Kg1 = Kbase + (size_t)(l0 + 4) * ND + sg * 8;
  const unsigned short* Vg0 = Vbase + (size_t)srow * NL + sg * 8;
  const unsigned short* Vg1 = Vbase + (size_t)(32 + srow) * NL + sg * 8;
  bf16x8 aq[2];
  int qw = q0 + wave * 16;
#pragma unroll
  for (int ks = 0; ks < 2; ++ks)
    aq[ks] = *(const bf16x8*)&Qb[(size_t)(b * NL + qw + lr) * ND + h * NDK + ks * 32 + lg * 8];
  const float* cbase = maskadd + b * NL;
  int nomask = __builtin_amdgcn_readfirstlane(maskall[b]);
  f32x4 accO[4] = {};
  float mst = -1e30f, lstl = 0.f;          // per-lane partial row-sum (16 keys/lane)
  int bconst = lg * 8 - wave * 16 - lr + 191 - q0;
  int src0 = (lane & 48) | ((lane >> 2) & 12);
  // prologue: stage tiles 0 and 1 into bufs 0, 1 (8 loads in flight)
  gl_lds16(Kg0, &Ks[0][tid * 8]);
  gl_lds16(Kg1, &Ks[0][2048 + tid * 8]);
  gl_lds16(Vg0, &Vs[0][tid * 8]);
  gl_lds16(Vg1, &Vs[0][2048 + tid * 8]);
  {
    size_t kok = (size_t)64 * ND, kov = 64;
    gl_lds16(Kg0 + kok, &Ks[1][tid * 8]);
    gl_lds16(Kg1 + kok, &Ks[1][2048 + tid * 8]);
    gl_lds16(Vg0 + kov, &Vs[1][tid * 8]);
    gl_lds16(Vg1 + kov, &Vs[1][2048 + tid * 8]);
  }
  asm volatile("s_waitcnt vmcnt(4) lgkmcnt(0)" ::: "memory");  // tile0 + biasw ready
  __builtin_amdgcn_s_barrier();
  // stage pointers for tile 2 onward (advance by constant stride per stage)
  const unsigned short* sk0 = Kg0 + (size_t)2 * 64 * ND;
  const unsigned short* sk1 = Kg1 + (size_t)2 * 64 * ND;
  const unsigned short* sv0 = Vg0 + 2 * 64;
  const unsigned short* sv1 = Vg1 + 2 * 64;

  auto body = [&](int kt_, auto CURc, auto PFc) {
    constexpr int CUR = decltype(CURc)::v;
    constexpr int PF  = decltype(PFc)::v;
    constexpr int ST  = (CUR + 2) % 3;
    float4 cv[2][2];
    if (!nomask) {
#pragma unroll
      for (int hf = 0; hf < 2; ++hf)
#pragma unroll
        for (int qd = 0; qd < 2; ++qd)
          cv[hf][qd] = *(const float4*)&cbase[kt_ * 64 + hf * 32 + lg * 8 + qd * 4];
    }
    if (PF) {
      gl_lds16(sk0, &Ks[ST][tid * 8]);
      gl_lds16(sk1, &Ks[ST][2048 + tid * 8]);
      gl_lds16(sv0, &Vs[ST][tid * 8]);
      gl_lds16(sv1, &Vs[ST][2048 + tid * 8]);
      sk0 += 64 * ND; sk1 += 64 * ND; sv0 += 64; sv1 += 64;
    }
    int kt64 = kt_ * 64;
    bool farlo = (kt64 + 63 < q0 - 90), farhi = (kt64 > q0 + 153);
    float ctile = farlo ? cFlo : (farhi ? cFhi : 0.0f);
    f32x4 s[4];
    __builtin_amdgcn_s_setprio(1);
    if (nomask && (farlo || farhi)) {
      const f32x4 z = {0.f, 0.f, 0.f, 0.f};
#pragma unroll
      for (int ni = 0; ni < 4; ++ni) {
        int kr = ni * 16 + lr;
        bf16x8 bk0 = *(const bf16x8*)&Ks[CUR][kr * 64 + ((lg ^ (lr & 7)) * 8)];
        bf16x8 bk1 = *(const bf16x8*)&Ks[CUR][kr * 64 + (((4 + lg) ^ (lr & 7)) * 8)];
        s[ni] = __builtin_amdgcn_mfma_f32_16x16x32_bf16(bk0, aq[0], z, 0, 0, 0);
        s[ni] = __builtin_amdgcn_mfma_f32_16x16x32_bf16(bk1, aq[1], s[ni], 0, 0, 0);
      }
    } else {
      if (farlo || farhi) {
#pragma unroll
        for (int ni = 0; ni < 4; ++ni)
#pragma unroll
          for (int r = 0; r < 4; ++r) s[ni][r] = 0.f;   // ctile folded later
      } else {
#pragma unroll
        for (int ni = 0; ni < 4; ++ni)
#pragma unroll
          for (int r = 0; r < 4; ++r)
            s[ni][r] = biasw[kt64 + (ni & 1) * 32 + (ni >> 1) * 4 + r + bconst];
      }
      if (!nomask) {
#pragma unroll
        for (int ni = 0; ni < 4; ++ni)
#pragma unroll
          for (int r = 0; r < 4; ++r)
            s[ni][r] += ((const float*)&cv[ni & 1][ni >> 1])[r];
      }
#pragma unroll
      for (int ni = 0; ni < 4; ++ni) {
        int kr = ni * 16 + lr;
        bf16x8 bk0 = *(const bf16x8*)&Ks[CUR][kr * 64 + ((lg ^ (lr & 7)) * 8)];
        bf16x8 bk1 = *(const bf16x8*)&Ks[CUR][kr * 64 + (((4 + lg) ^ (lr & 7)) * 8)];
        s[ni] = __builtin_amdgcn_mfma_f32_16x16x32_bf16(bk0, aq[0], s[ni], 0, 0, 0);
        s[ni] = __builtin_amdgcn_mfma_f32_16x16x32_bf16(bk1, aq[1], s[ni], 0, 0, 0);
      }
    }
    __builtin_amdgcn_s_setprio(0);
    // lane-local max: max3-fusable triple groupings (16 values, 8 ops, depth 3)
    float a0 = fmaxf(fmaxf(s[0][0], s[0][1]), s[0][2]);
    float a1 = fmaxf(fmaxf(s[0][3], s[1][0]), s[1][1]);
    float a2 = fmaxf(fmaxf(s[1][2], s[1][3]), s[2][0]);
    float a3 = fmaxf(fmaxf(s[2][1], s[2][2]), s[2][3]);
    float a4 = fmaxf(fmaxf(s[3][0], s[3][1]), s[3][2]);
    float lm = fmaxf(fmaxf(fmaxf(a0, a1), a2), fmaxf(fmaxf(a3, a4), s[3][3]));
    if (!__all(lm + ctile - mst <= 8.0f)) {
      float pmax = fmaxf(lm, __shfl_xor(lm, 16));
      pmax = xmax32(pmax);
      float pm2 = pmax + ctile;
      float mnew = fmaxf(mst, pm2);
      float sc = fexp2(mst - mnew);
      float scB[4];
#pragma unroll
      for (int r = 0; r < 4; ++r) scB[r] = __shfl(sc, src0 | r);
#pragma unroll
      for (int ni = 0; ni < 4; ++ni)
#pragma unroll
        for (int r = 0; r < 4; ++r) accO[ni][r] *= scB[r];
      lstl *= sc;
      mst = mnew;
    }
    float msub = mst - ctile;
#pragma unroll
    for (int ni = 0; ni < 4; ++ni)
#pragma unroll
      for (int r = 0; r < 4; ++r) s[ni][r] = fexp2(s[ni][r] - msub);
    {
      f32x4 ta = s[0] + s[1];
      f32x4 tb = s[2] + s[3];
      ta = ta + tb;
      lstl += (ta[0] + ta[1]) + (ta[2] + ta[3]);
    }
    // pack P: lane's 16 values are exactly its PV A-fragments (key permutation)
    unsigned pw[8];
#pragma unroll
    for (int ni = 0; ni < 4; ++ni) {
      unsigned a, c;
      asm("v_cvt_pk_bf16_f32 %0, %1, %2" : "=v"(a) : "v"(s[ni][0]), "v"(s[ni][1]));
      asm("v_cvt_pk_bf16_f32 %0, %1, %2" : "=v"(c) : "v"(s[ni][2]), "v"(s[ni][3]));
      pw[ni * 2] = a; pw[ni * 2 + 1] = c;
    }
    u32x4 apw0 = {pw[0], pw[1], pw[4], pw[5]};
    u32x4 apw1 = {pw[2], pw[3], pw[6], pw[7]};
    bf16x8 ap0 = __builtin_bit_cast(bf16x8, apw0);
    bf16x8 ap1 = __builtin_bit_cast(bf16x8, apw1);
    // O += P @ V
    __builtin_amdgcn_s_setprio(1);
#pragma unroll
    for (int ni = 0; ni < 4; ++ni) {
      int vr = ni * 16 + lr;
      bf16x8 bv0 = *(const bf16x8*)&Vs[CUR][vr * 64 + ((lg ^ (lr & 7)) * 8)];
      bf16x8 bv1 = *(const bf16x8*)&Vs[CUR][vr * 64 + (((4 + lg) ^ (lr & 7)) * 8)];
      accO[ni] = __builtin_amdgcn_mfma_f32_16x16x32_bf16(ap0, bv0, accO[ni], 0, 0, 0);
      accO[ni] = __builtin_amdgcn_mfma_f32_16x16x32_bf16(ap1, bv1, accO[ni], 0, 0, 0);
    }
    __builtin_amdgcn_s_setprio(0);
    if (PF) asm volatile("s_waitcnt vmcnt(4)" ::: "memory");
    else    asm volatile("s_waitcnt vmcnt(0)" ::: "memory");
    __builtin_amdgcn_s_barrier();
  };

  for (int kt = 0; kt < 30; kt += 3) {   // tile kt uses buf kt%3; stages kt+2
    body(kt,     IC<0>{}, IC<1>{});
    body(kt + 1, IC<1>{}, IC<1>{});
    body(kt + 2, IC<2>{}, IC<1>{});
  }
  body(30, IC<0>{}, IC<0>{});
  body(31, IC<1>{}, IC<0>{});

  // epilogue: one cross-lane row-sum, then broadcast 1/l to accO's row layout
  float lst = lstl + __shfl_xor(lstl, 16);
  lst = xsum32(lst);
  float linv = 1.0f / lst;
  float lB[4];
#pragma unroll
  for (int r = 0; r < 4; ++r) lB[r] = __shfl(linv, src0 | r);
#pragma unroll
  for (int ni = 0; ni < 4; ++ni)
#pragma unroll
    for (int r = 0; r < 4; ++r) {
      int qg = qw + lg * 4 + r;
      int col = h * NDK + ni * 16 + lr;
      Ob[(size_t)(b * NL + qg) * ND + col] = f2bf(accO[ni][r] * lB[r]);
    }
}

extern "C" void kernel_launch(void* const* d_in, const int* in_sizes, int n_in,
                              void* d_out, int out_size, void* d_ws, size_t ws_size,
                              hipStream_t stream) {
  const float* query  = (const float*)d_in[0];
  const float* keyval = (const float*)d_in[1];
  const int*   mask   = (const int*)d_in[2];
  const float* Wq     = (const float*)d_in[3];
  const float* Wk     = (const float*)d_in[4];
  const float* Wv     = (const float*)d_in[5];
  const float* Wo     = (const float*)d_in[6];
  const float* rel    = (const float*)d_in[7];

  char* ws = (char*)d_ws;
  unsigned short* q_bf  = (unsigned short*)(ws);              // 4096x768 bf16
  unsigned short* kv_bf = (unsigned short*)(ws + 6291456);
  unsigned short* Wq_t  = (unsigned short*)(ws + 12582912);   // [N][K] bf16 (x 0.125*log2e)
  unsigned short* Wk_t  = (unsigned short*)(ws + 13762560);
  unsigned short* Wv_t  = (unsigned short*)(ws + 14942208);
  unsigned short* Wo_t  = (unsigned short*)(ws + 16121856);
  unsigned short* Qb    = (unsigned short*)(ws + 17301504);   // [B,L,H,DK]
  unsigned short* Kb    = (unsigned short*)(ws + 23592960);
  unsigned short* Vt    = (unsigned short*)(ws + 29884416);   // [B,768,L]
  unsigned short* Ob    = (unsigned short*)(ws + 36175872);   // [B,L,H*DK]
  float* bias_tab       = (float*)(ws + 42467328);            // [H][4095], x log2e
  float* maskadd        = (float*)(ws + 42663936);            // [B][L]
  int*   maskall        = (int*)(ws + 42680320);              // [B]

  k_prep<<<dim3(8642), dim3(256), 0, stream>>>(query, keyval, Wq, Wk, Wv, Wo, rel, mask,
                                               q_bf, kv_bf, Wq_t, Wk_t, Wv_t, Wo_t,
                                               bias_tab, maskadd, maskall);
  k_gemm_qkv<<<dim3(32, 24), dim3(256), 0, stream>>>(q_bf, kv_bf, Wq_t, Qb, Kb, Vt);
  k_attn<<<dim3(768), dim3(256), 0, stream>>>(Qb, Kb, Vt, bias_tab, maskadd, maskall, Ob);
  k_gemm<<<dim3(768), dim3(256), 0, stream>>>(Ob, Wo_t, (float*)d_out, NM, ND, ND);
}

// Round 20
// 84.252 us; speedup vs baseline: 1.1717x; 1.0902x over previous
//
#include <hip/hip_runtime.h>
#include <stdint.h>

typedef __attribute__((ext_vector_type(8))) short bf16x8;
typedef __attribute__((ext_vector_type(4))) float f32x4;
typedef __attribute__((ext_vector_type(4))) unsigned int u32x4;

#define NB 2
#define NL 2048
#define ND 768
#define NH 12
#define NDK 64
#define NM 4096   // NB*NL
#define LOG2E 1.4426950408889634f

template<int N> struct IC { static constexpr int v = N; };

__device__ __forceinline__ unsigned short f2bf(float f) {
  unsigned u = __builtin_bit_cast(unsigned, f);
  u += 0x7FFFu + ((u >> 16) & 1u);          // RNE
  return (unsigned short)(u >> 16);
}

__device__ __forceinline__ float fexp2(float x) {
  float r;
  asm("v_exp_f32 %0, %1" : "=v"(r) : "v"(x));
  return r;
}

__device__ __forceinline__ float xmax32(float x) { return fmaxf(x, __shfl_xor(x, 32)); }
__device__ __forceinline__ float xsum32(float x) { return x + __shfl_xor(x, 32); }

__device__ __forceinline__ void gl_lds16(const unsigned short* g, unsigned short* l) {
  __builtin_amdgcn_global_load_lds((const __attribute__((address_space(1))) void*)g,
                                   (__attribute__((address_space(3))) void*)l, 16, 0, 0);
}

// ---- merged prep: conv (0..6143) | wt (6144..8447) | bias (8448..8639) | maskadd (8640..8641)
__global__ __launch_bounds__(256) void k_prep(const float* __restrict__ query,
                                              const float* __restrict__ keyval,
                                              const float* __restrict__ Wq,
                                              const float* __restrict__ Wk,
                                              const float* __restrict__ Wv,
                                              const float* __restrict__ Wo,
                                              const float* __restrict__ rel_emb,
                                              const int* __restrict__ mask,
                                              unsigned short* __restrict__ q_bf,
                                              unsigned short* __restrict__ kv_bf,
                                              unsigned short* __restrict__ Wq_t,
                                              unsigned short* __restrict__ Wk_t,
                                              unsigned short* __restrict__ Wv_t,
                                              unsigned short* __restrict__ Wo_t,
                                              float* __restrict__ bias_tab,
                                              float* __restrict__ maskadd,
                                              int* __restrict__ maskall) {
  __shared__ float shbuf[32 * 33];
  int blk = blockIdx.x, tid = threadIdx.x;
  if (blk < 6144) {
    int y = blk / 3072;
    int i = (blk - y * 3072) * 256 + tid;
    const float* src = y ? keyval : query;
    unsigned short* dst = y ? kv_bf : q_bf;
    float4 v = ((const float4*)src)[i];
    ushort4 o;
    o.x = f2bf(v.x); o.y = f2bf(v.y); o.z = f2bf(v.z); o.w = f2bf(v.w);
    ((ushort4*)dst)[i] = o;
  } else if (blk < 8448) {
    int rel = blk - 6144;
    int z = rel / 576, r2 = rel - z * 576;
    int bx = (r2 % 24) * 32, by = (r2 / 24) * 32;
    const float* w = (z == 0) ? Wq : (z == 1) ? Wk : (z == 2) ? Wv : Wo;
    unsigned short* o = (z == 0) ? Wq_t : (z == 1) ? Wk_t : (z == 2) ? Wv_t : Wo_t;
    float scale = (z == 0) ? 0.125f * LOG2E : 1.0f;
    int tx = tid & 31, ty = tid >> 5;
    float (*t)[33] = (float(*)[33])shbuf;
    for (int r = 0; r < 32; r += 8)
      t[ty + r][tx] = w[(by + ty + r) * ND + bx + tx];
    __syncthreads();
    for (int r = 0; r < 32; r += 8)
      o[(bx + ty + r) * ND + by + tx] = f2bf(t[tx][ty + r] * scale);
  } else if (blk < 8640) {
    int idx = (blk - 8448) * 256 + tid;
    if (idx >= 4095 * NH) return;
    int h = idx % NH;
    int di = idx / NH;
    int rel = di - 2047;          // rel = k - q
    int n = -rel;
    int ret = 0;
    if (n < 0) { ret = 16; n = -n; }
    int b;
    if (n < 8) {
      b = ret + n;
    } else {
      int v = (n >= 91) ? 7 : (n >= 64) ? 6 : (n >= 46) ? 5 : (n >= 32) ? 4
            : (n >= 23) ? 3 : (n >= 16) ? 2 : (n >= 12) ? 1 : 0;
      b = ret + 8 + v;
    }
    bias_tab[h * 4095 + di] = rel_emb[b * NH + h] * LOG2E;
  } else {
    int b = blk - 8640;
    int* red = (int*)shbuf;
    int acc = 1;
    for (int i = tid; i < NL; i += 256) {
      int m = mask[b * NL + i];
      maskadd[b * NL + i] = m ? 0.0f : -1e30f;
      acc &= (m != 0) ? 1 : 0;
    }
    red[tid] = acc;
    __syncthreads();
    for (int s2 = 128; s2 > 0; s2 >>= 1) {
      if (tid < s2) red[tid] &= red[tid + s2];
      __syncthreads();
    }
    if (tid == 0) maskall[b] = red[0];
  }
}

// ---- fused QKV GEMM, 128x96 tile, grid (32,24) = 768 = 3/CU. A-only double
// buffer (A is the HBM stream; B/weights are L2-hot): issue A(t+1) before
// compute(t) so its ~700cy HBM latency flies under the MFMAs; B(t+1) staged
// after the barrier with only its L2-short wait. LDS 44 KB -> 3 blocks/CU.
// NOTE: buffer select via pointer arithmetic (LDS pointer ARRAYS fail to compile:
// "unsupported expression in static initializer" addrspacecast).
__global__ __launch_bounds__(256) void k_gemm_qkv(const unsigned short* __restrict__ q_bf,
                                                  const unsigned short* __restrict__ kv_bf,
                                                  const unsigned short* __restrict__ Wt,
                                                  unsigned short* __restrict__ Qb,
                                                  unsigned short* __restrict__ Kb,
                                                  unsigned short* __restrict__ Vt) {
  __shared__ unsigned short S[22528];   // A0:[0,8192) A1:[8192,16384) B:[16384,22528)
  unsigned short* Bs = S + 16384;
  int tid = threadIdx.x;
  int wave = tid >> 6, lane = tid & 63;
  int lr = lane & 15, lg = lane >> 4;
  int m0 = blockIdx.x * 128;
  int z = blockIdx.y >> 3;                 // 0=Q, 1=K, 2=V
  int nc0 = (blockIdx.y & 7) * 96;         // col within the 768-wide section
  const unsigned short* A  = (z == 0) ? q_bf : kv_bf;
  const unsigned short* Bt = Wt + (size_t)blockIdx.y * 96 * ND;
  int wm = (wave >> 1) * 64, wn = (wave & 1) * 48;
  int srow = tid >> 3, spc = tid & 7;
  int sg = spc ^ (srow & 7);
  const unsigned short* Ag = A  + (size_t)(m0 + srow) * ND + sg * 8;
  const unsigned short* Bg = Bt + (size_t)srow * ND + sg * 8;
  f32x4 acc[4][3] = {};
  const int KT = ND / 64;
  // prologue: stage A0 + B0
#pragma unroll
  for (int s = 0; s < 4; ++s)
    gl_lds16(Ag + (size_t)(s * 32) * ND, &S[s * 2048 + tid * 8]);
#pragma unroll
  for (int s = 0; s < 3; ++s)
    gl_lds16(Bg + (size_t)(s * 32) * ND, &Bs[s * 2048 + tid * 8]);
  __syncthreads();
  int cur = 0;
  for (int t = 0; t < KT; ++t) {
    unsigned short* Acur = S + (cur ? 8192 : 0);
    unsigned short* Anxt = S + (cur ? 0 : 8192);
    if (t + 1 < KT) {                       // A(t+1) flies under compute(t)
      int k0 = (t + 1) * 64;
#pragma unroll
      for (int s = 0; s < 4; ++s)
        gl_lds16(Ag + (size_t)(s * 32) * ND + k0, &Anxt[s * 2048 + tid * 8]);
    }
#pragma unroll
    for (int ks = 0; ks < 2; ++ks) {
      bf16x8 af[4], bfr[3];
#pragma unroll
      for (int i = 0; i < 4; ++i) {
        int ar = wm + i * 16 + lr;
        af[i] = *(const bf16x8*)&Acur[ar * 64 + (((ks * 4 + lg) ^ (ar & 7)) * 8)];
      }
#pragma unroll
      for (int i = 0; i < 3; ++i) {
        int br = wn + i * 16 + lr;
        bfr[i] = *(const bf16x8*)&Bs[br * 64 + (((ks * 4 + lg) ^ (br & 7)) * 8)];
      }
#pragma unroll
      for (int mi = 0; mi < 4; ++mi)
#pragma unroll
        for (int ni = 0; ni < 3; ++ni)
          acc[mi][ni] = __builtin_amdgcn_mfma_f32_16x16x32_bf16(af[mi], bfr[ni], acc[mi][ni], 0, 0, 0);
    }
    __syncthreads();                        // A(t+1) complete; Bs reads done
    if (t + 1 < KT) {                       // B(t+1): L2-hot, short wait
      int k0 = (t + 1) * 64;
#pragma unroll
      for (int s = 0; s < 3; ++s)
        gl_lds16(Bg + (size_t)(s * 32) * ND + k0, &Bs[s * 2048 + tid * 8]);
      asm volatile("s_waitcnt vmcnt(0)" ::: "memory");
      __builtin_amdgcn_s_barrier();
    }
    cur ^= 1;
  }
  if (z == 2) {
    // transpose through LDS: T[col][row], chunk-XOR swizzle (chunk ^= col&7)
    unsigned short* T = S;                 // 24 KB fits in the 44 KB region
#pragma unroll
    for (int mi = 0; mi < 4; ++mi)
#pragma unroll
      for (int ni = 0; ni < 3; ++ni) {
        int col  = wn + ni * 16 + lr;      // dk within tile, 0..95
        int rowb = wm + mi * 16 + lg * 4;  // l within tile, 4 consecutive rows
        ushort4 v4;
        v4.x = f2bf(acc[mi][ni][0]);
        v4.y = f2bf(acc[mi][ni][1]);
        v4.z = f2bf(acc[mi][ni][2]);
        v4.w = f2bf(acc[mi][ni][3]);
        int addr = col * 128 + (((rowb >> 3) ^ (col & 7)) * 8) + (rowb & 7);
        *(ushort4*)&T[addr] = v4;          // 8B aligned: (rowb&7) in {0,4}
      }
    __syncthreads();
    int bb = m0 >> 11;
    unsigned short* vdst = Vt + (((size_t)bb * ND + nc0) << 11) + (m0 & 2047);
#pragma unroll
    for (int pass = 0; pass < 6; ++pass) {
      int col = (tid >> 4) + pass * 16;    // 16 cols per pass, 96 total
      int cc = tid & 15;                   // 16 chunks of 8 elems per col
      u32x4 val = *(const u32x4*)&T[col * 128 + ((cc ^ (col & 7)) * 8)];
      *(u32x4*)&vdst[((size_t)col << 11) + cc * 8] = val;  // 256B/16 lanes contiguous
    }
  } else {
#pragma unroll
    for (int mi = 0; mi < 4; ++mi)
#pragma unroll
      for (int ni = 0; ni < 3; ++ni)
#pragma unroll
        for (int r = 0; r < 4; ++r) {
          int row = m0 + wm + mi * 16 + lg * 4 + r;
          int col = nc0 + wn + ni * 16 + lr;
          unsigned short v = f2bf(acc[mi][ni][r]);
          if (z == 0) Qb[(size_t)row * ND + col] = v;
          else        Kb[(size_t)row * ND + col] = v;
        }
  }
}

// ---- out-proj GEMM: C[M,N] fp32 = A[M,K] bf16 * Bt[N,K]^T. 64x64 tile, flat grid
// 768 + XCD swizzle + dbuf LDS with prefetch-before-compute.
__global__ __launch_bounds__(256) void k_gemm(const unsigned short* __restrict__ A,
                                              const unsigned short* __restrict__ Bt,
                                              float* __restrict__ Cout,
                                              int Msz, int Nsz, int Ksz) {
  __shared__ unsigned short As[2][4096];   // [64][64] per buf
  __shared__ unsigned short Bs[2][4096];
  int flat = blockIdx.x;
  int nf = (flat & 7) * 96 + (flat >> 3);   // bijective: 768 = 8*96
  int px = nf / 12;                          // A-panel (0..63)
  int y  = nf - px * 12;                     // N-column (0..11)
  int tid = threadIdx.x;
  int wave = tid >> 6, lane = tid & 63;
  int lr = lane & 15, lg = lane >> 4;
  int m0 = px * 64, n0 = y * 64;
  int wm = (wave >> 1) * 32, wn = (wave & 1) * 32;
  int srow = tid >> 3, spc = tid & 7;
  int sg = spc ^ (srow & 7);
  const unsigned short* Ag = A  + (size_t)(m0 + srow) * Ksz + sg * 8;
  const unsigned short* Bg = Bt + (size_t)(n0 + srow) * Ksz + sg * 8;
  f32x4 acc[2][2] = {};
  const int KT = Ksz >> 6;
#pragma unroll
  for (int s = 0; s < 2; ++s) {
    gl_lds16(Ag + (size_t)(s * 32) * Ksz, &As[0][s * 2048 + tid * 8]);
    gl_lds16(Bg + (size_t)(s * 32) * Ksz, &Bs[0][s * 2048 + tid * 8]);
  }
  __syncthreads();
  int cur = 0;
  for (int t = 0; t < KT; ++t) {
    if (t + 1 < KT) {
      int k0 = (t + 1) << 6;
#pragma unroll
      for (int s = 0; s < 2; ++s) {
        gl_lds16(Ag + (size_t)(s * 32) * Ksz + k0, &As[cur ^ 1][s * 2048 + tid * 8]);
        gl_lds16(Bg + (size_t)(s * 32) * Ksz + k0, &Bs[cur ^ 1][s * 2048 + tid * 8]);
      }
    }
#pragma unroll
    for (int ks = 0; ks < 2; ++ks) {
      bf16x8 af[2], bfr[2];
#pragma unroll
      for (int i = 0; i < 2; ++i) {
        int ar = wm + i * 16 + lr;
        af[i] = *(const bf16x8*)&As[cur][ar * 64 + (((ks * 4 + lg) ^ (ar & 7)) * 8)];
        int br = wn + i * 16 + lr;
        bfr[i] = *(const bf16x8*)&Bs[cur][br * 64 + (((ks * 4 + lg) ^ (br & 7)) * 8)];
      }
#pragma unroll
      for (int mi = 0; mi < 2; ++mi)
#pragma unroll
        for (int ni = 0; ni < 2; ++ni)
          acc[mi][ni] = __builtin_amdgcn_mfma_f32_16x16x32_bf16(af[mi], bfr[ni], acc[mi][ni], 0, 0, 0);
    }
    __syncthreads();
    cur ^= 1;
  }
#pragma unroll
  for (int mi = 0; mi < 2; ++mi)
#pragma unroll
    for (int ni = 0; ni < 2; ++ni)
#pragma unroll
      for (int r = 0; r < 4; ++r) {
        int row = m0 + wm + mi * 16 + lg * 4 + r;
        int col = n0 + wn + ni * 16 + lr;
        Cout[(size_t)row * Nsz + col] = acc[mi][ni][r];
      }
}

// ---- fused flash attention (R18 structure, setprio removed per m190): swapped-
// QK^T (exp2), 3-buffer counted-vmcnt pipeline, far-tile zero-C bias, lane-local
// softmax, XCD swizzle.
__global__ __launch_bounds__(256, 3) void k_attn(const unsigned short* __restrict__ Qb,
                                                 const unsigned short* __restrict__ Kb,
                                                 const unsigned short* __restrict__ Vt,
                                                 const float* __restrict__ bias_tab,
                                                 const float* __restrict__ maskadd,
                                                 const int* __restrict__ maskall,
                                                 unsigned short* __restrict__ Ob) {
  __shared__ unsigned short Ks[3][4096];   // [64 phys keys][64 dk], XOR-swizzled chunks
  __shared__ unsigned short Vs[3][4096];   // [64 dk][64 keys natural], XOR-swizzled
  __shared__ float biasw[384];             // near band: biasw[d+191]
  int flat = blockIdx.x;
  int nf = (flat & 7) * 96 + (flat >> 3);
  int qt = nf & 31, bh = nf >> 5;
  int b = bh / NH, h = bh % NH;
  int tid = threadIdx.x, wave = tid >> 6, lane = tid & 63;
  int lr = lane & 15, lg = lane >> 4;
  int q0 = qt * 64;
  for (int i = tid; i < 383; i += 256) biasw[i] = bias_tab[h * 4095 + 1856 + i];
  float cFlo = bias_tab[h * 4095];          // d <= -91 saturated (bucket 15)
  float cFhi = bias_tab[h * 4095 + 4094];   // d >= +91 saturated (bucket 31)
  const unsigned short* Kbase = Kb + (size_t)(b * NL) * ND + h * NDK;
  const unsigned short* Vbase = Vt + (size_t)(b * NH + h) * NDK * NL;
  int srow = tid >> 3, spc = tid & 7;
  int sg = spc ^ (srow & 7);
  // key permutation: phys row srow stores logical key l0; +32 phys -> l0+4
  int l0 = (srow >> 4) * 32 + ((srow >> 2) & 3) * 8 + (srow & 3);
  const unsigned short* Kg0 = Kbase + (size_t)l0 * ND + sg * 8;
  const unsigned short* Kg1 = Kbase + (size_t)(l0 + 4) * ND + sg * 8;
  const unsigned short* Vg0 = Vbase + (size_t)srow * NL + sg * 8;
  const unsigned short* Vg1 = Vbase + (size_t)(32 + srow) * NL + sg * 8;
  bf16x8 aq[2];
  int qw = q0 + wave * 16;
#pragma unroll
  for (int ks = 0; ks < 2; ++ks)
    aq[ks] = *(const bf16x8*)&Qb[(size_t)(b * NL + qw + lr) * ND + h * NDK + ks * 32 + lg * 8];
  const float* cbase = maskadd + b * NL;
  int nomask = __builtin_amdgcn_readfirstlane(maskall[b]);
  f32x4 accO[4] = {};
  float mst = -1e30f, lstl = 0.f;          // per-lane partial row-sum (16 keys/lane)
  int bconst = lg * 8 - wave * 16 - lr + 191 - q0;
  int src0 = (lane & 48) | ((lane >> 2) & 12);
  // prologue: stage tiles 0 and 1 into bufs 0, 1 (8 loads in flight)
  gl_lds16(Kg0, &Ks[0][tid * 8]);
  gl_lds16(Kg1, &Ks[0][2048 + tid * 8]);
  gl_lds16(Vg0, &Vs[0][tid * 8]);
  gl_lds16(Vg1, &Vs[0][2048 + tid * 8]);
  {
    size_t kok = (size_t)64 * ND, kov = 64;
    gl_lds16(Kg0 + kok, &Ks[1][tid * 8]);
    gl_lds16(Kg1 + kok, &Ks[1][2048 + tid * 8]);
    gl_lds16(Vg0 + kov, &Vs[1][tid * 8]);
    gl_lds16(Vg1 + kov, &Vs[1][2048 + tid * 8]);
  }
  asm volatile("s_waitcnt vmcnt(4) lgkmcnt(0)" ::: "memory");  // tile0 + biasw ready
  __builtin_amdgcn_s_barrier();
  // stage pointers for tile 2 onward (advance by constant stride per stage)
  const unsigned short* sk0 = Kg0 + (size_t)2 * 64 * ND;
  const unsigned short* sk1 = Kg1 + (size_t)2 * 64 * ND;
  const unsigned short* sv0 = Vg0 + 2 * 64;
  const unsigned short* sv1 = Vg1 + 2 * 64;

  auto body = [&](int kt_, auto CURc, auto PFc) {
    constexpr int CUR = decltype(CURc)::v;
    constexpr int PF  = decltype(PFc)::v;
    constexpr int ST  = (CUR + 2) % 3;
    float4 cv[2][2];
    if (!nomask) {
#pragma unroll
      for (int hf = 0; hf < 2; ++hf)
#pragma unroll
        for (int qd = 0; qd < 2; ++qd)
          cv[hf][qd] = *(const float4*)&cbase[kt_ * 64 + hf * 32 + lg * 8 + qd * 4];
    }
    if (PF) {
      gl_lds16(sk0, &Ks[ST][tid * 8]);
      gl_lds16(sk1, &Ks[ST][2048 + tid * 8]);
      gl_lds16(sv0, &Vs[ST][tid * 8]);
      gl_lds16(sv1, &Vs[ST][2048 + tid * 8]);
      sk0 += 64 * ND; sk1 += 64 * ND; sv0 += 64; sv1 += 64;
    }
    int kt64 = kt_ * 64;
    bool farlo = (kt64 + 63 < q0 - 90), farhi = (kt64 > q0 + 153);
    float ctile = farlo ? cFlo : (farhi ? cFhi : 0.0f);
    f32x4 s[4];
    if (nomask && (farlo || farhi)) {
      const f32x4 z = {0.f, 0.f, 0.f, 0.f};
#pragma unroll
      for (int ni = 0; ni < 4; ++ni) {
        int kr = ni * 16 + lr;
        bf16x8 bk0 = *(const bf16x8*)&Ks[CUR][kr * 64 + ((lg ^ (lr & 7)) * 8)];
        bf16x8 bk1 = *(const bf16x8*)&Ks[CUR][kr * 64 + (((4 + lg) ^ (lr & 7)) * 8)];
        s[ni] = __builtin_amdgcn_mfma_f32_16x16x32_bf16(bk0, aq[0], z, 0, 0, 0);
        s[ni] = __builtin_amdgcn_mfma_f32_16x16x32_bf16(bk1, aq[1], s[ni], 0, 0, 0);
      }
    } else {
      if (farlo || farhi) {
#pragma unroll
        for (int ni = 0; ni < 4; ++ni)
#pragma unroll
          for (int r = 0; r < 4; ++r) s[ni][r] = 0.f;   // ctile folded later
      } else {
#pragma unroll
        for (int ni = 0; ni < 4; ++ni)
#pragma unroll
          for (int r = 0; r < 4; ++r)
            s[ni][r] = biasw[kt64 + (ni & 1) * 32 + (ni >> 1) * 4 + r + bconst];
      }
      if (!nomask) {
#pragma unroll
        for (int ni = 0; ni < 4; ++ni)
#pragma unroll
          for (int r = 0; r < 4; ++r)
            s[ni][r] += ((const float*)&cv[ni & 1][ni >> 1])[r];
      }
#pragma unroll
      for (int ni = 0; ni < 4; ++ni) {
        int kr = ni * 16 + lr;
        bf16x8 bk0 = *(const bf16x8*)&Ks[CUR][kr * 64 + ((lg ^ (lr & 7)) * 8)];
        bf16x8 bk1 = *(const bf16x8*)&Ks[CUR][kr * 64 + (((4 + lg) ^ (lr & 7)) * 8)];
        s[ni] = __builtin_amdgcn_mfma_f32_16x16x32_bf16(bk0, aq[0], s[ni], 0, 0, 0);
        s[ni] = __builtin_amdgcn_mfma_f32_16x16x32_bf16(bk1, aq[1], s[ni], 0, 0, 0);
      }
    }
    // lane-local max: max3-fusable triple groupings (16 values, 8 ops, depth 3)
    float a0 = fmaxf(fmaxf(s[0][0], s[0][1]), s[0][2]);
    float a1 = fmaxf(fmaxf(s[0][3], s[1][0]), s[1][1]);
    float a2 = fmaxf(fmaxf(s[1][2], s[1][3]), s[2][0]);
    float a3 = fmaxf(fmaxf(s[2][1], s[2][2]), s[2][3]);
    float a4 = fmaxf(fmaxf(s[3][0], s[3][1]), s[3][2]);
    float lm = fmaxf(fmaxf(fmaxf(a0, a1), a2), fmaxf(fmaxf(a3, a4), s[3][3]));
    if (!__all(lm + ctile - mst <= 8.0f)) {
      float pmax = fmaxf(lm, __shfl_xor(lm, 16));
      pmax = xmax32(pmax);
      float pm2 = pmax + ctile;
      float mnew = fmaxf(mst, pm2);
      float sc = fexp2(mst - mnew);
      float scB[4];
#pragma unroll
      for (int r = 0; r < 4; ++r) scB[r] = __shfl(sc, src0 | r);
#pragma unroll
      for (int ni = 0; ni < 4; ++ni)
#pragma unroll
        for (int r = 0; r < 4; ++r) accO[ni][r] *= scB[r];
      lstl *= sc;
      mst = mnew;
    }
    float msub = mst - ctile;
#pragma unroll
    for (int ni = 0; ni < 4; ++ni)
#pragma unroll
      for (int r = 0; r < 4; ++r) s[ni][r] = fexp2(s[ni][r] - msub);
    {
      f32x4 ta = s[0] + s[1];
      f32x4 tb = s[2] + s[3];
      ta = ta + tb;
      lstl += (ta[0] + ta[1]) + (ta[2] + ta[3]);
    }
    // pack P: lane's 16 values are exactly its PV A-fragments (key permutation)
    unsigned pw[8];
#pragma unroll
    for (int ni = 0; ni < 4; ++ni) {
      unsigned a, c;
      asm("v_cvt_pk_bf16_f32 %0, %1, %2" : "=v"(a) : "v"(s[ni][0]), "v"(s[ni][1]));
      asm("v_cvt_pk_bf16_f32 %0, %1, %2" : "=v"(c) : "v"(s[ni][2]), "v"(s[ni][3]));
      pw[ni * 2] = a; pw[ni * 2 + 1] = c;
    }
    u32x4 apw0 = {pw[0], pw[1], pw[4], pw[5]};
    u32x4 apw1 = {pw[2], pw[3], pw[6], pw[7]};
    bf16x8 ap0 = __builtin_bit_cast(bf16x8, apw0);
    bf16x8 ap1 = __builtin_bit_cast(bf16x8, apw1);
    // O += P @ V
#pragma unroll
    for (int ni = 0; ni < 4; ++ni) {
      int vr = ni * 16 + lr;
      bf16x8 bv0 = *(const bf16x8*)&Vs[CUR][vr * 64 + ((lg ^ (lr & 7)) * 8)];
      bf16x8 bv1 = *(const bf16x8*)&Vs[CUR][vr * 64 + (((4 + lg) ^ (lr & 7)) * 8)];
      accO[ni] = __builtin_amdgcn_mfma_f32_16x16x32_bf16(ap0, bv0, accO[ni], 0, 0, 0);
      accO[ni] = __builtin_amdgcn_mfma_f32_16x16x32_bf16(ap1, bv1, accO[ni], 0, 0, 0);
    }
    if (PF) asm volatile("s_waitcnt vmcnt(4)" ::: "memory");
    else    asm volatile("s_waitcnt vmcnt(0)" ::: "memory");
    __builtin_amdgcn_s_barrier();
  };

  for (int kt = 0; kt < 30; kt += 3) {   // tile kt uses buf kt%3; stages kt+2
    body(kt,     IC<0>{}, IC<1>{});
    body(kt + 1, IC<1>{}, IC<1>{});
    body(kt + 2, IC<2>{}, IC<1>{});
  }
  body(30, IC<0>{}, IC<0>{});
  body(31, IC<1>{}, IC<0>{});

  // epilogue: one cross-lane row-sum, then broadcast 1/l to accO's row layout
  float lst = lstl + __shfl_xor(lstl, 16);
  lst = xsum32(lst);
  float linv = 1.0f / lst;
  float lB[4];
#pragma unroll
  for (int r = 0; r < 4; ++r) lB[r] = __shfl(linv, src0 | r);
#pragma unroll
  for (int ni = 0; ni < 4; ++ni)
#pragma unroll
    for (int r = 0; r < 4; ++r) {
      int qg = qw + lg * 4 + r;
      int col = h * NDK + ni * 16 + lr;
      Ob[(size_t)(b * NL + qg) * ND + col] = f2bf(accO[ni][r] * lB[r]);
    }
}

extern "C" void kernel_launch(void* const* d_in, const int* in_sizes, int n_in,
                              void* d_out, int out_size, void* d_ws, size_t ws_size,
                              hipStream_t stream) {
  const float* query  = (const float*)d_in[0];
  const float* keyval = (const float*)d_in[1];
  const int*   mask   = (const int*)d_in[2];
  const float* Wq     = (const float*)d_in[3];
  const float* Wk     = (const float*)d_in[4];
  const float* Wv     = (const float*)d_in[5];
  const float* Wo     = (const float*)d_in[6];
  const float* rel    = (const float*)d_in[7];

  char* ws = (char*)d_ws;
  unsigned short* q_bf  = (unsigned short*)(ws);              // 4096x768 bf16
  unsigned short* kv_bf = (unsigned short*)(ws + 6291456);
  unsigned short* Wq_t  = (unsigned short*)(ws + 12582912);   // [N][K] bf16 (x 0.125*log2e)
  unsigned short* Wk_t  = (unsigned short*)(ws + 13762560);
  unsigned short* Wv_t  = (unsigned short*)(ws + 14942208);
  unsigned short* Wo_t  = (unsigned short*)(ws + 16121856);
  unsigned short* Qb    = (unsigned short*)(ws + 17301504);   // [B,L,H,DK]
  unsigned short* Kb    = (unsigned short*)(ws + 23592960);
  unsigned short* Vt    = (unsigned short*)(ws + 29884416);   // [B,768,L]
  unsigned short* Ob    = (unsigned short*)(ws + 36175872);   // [B,L,H*DK]
  float* bias_tab       = (float*)(ws + 42467328);            // [H][4095], x log2e
  float* maskadd        = (float*)(ws + 42663936);            // [B][L]
  int*   maskall        = (int*)(ws + 42680320);              // [B]

  k_prep<<<dim3(8642), dim3(256), 0, stream>>>(query, keyval, Wq, Wk, Wv, Wo, rel, mask,
                                               q_bf, kv_bf, Wq_t, Wk_t, Wv_t, Wo_t,
                                               bias_tab, maskadd, maskall);
  k_gemm_qkv<<<dim3(32, 24), dim3(256), 0, stream>>>(q_bf, kv_bf, Wq_t, Qb, Kb, Vt);
  k_attn<<<dim3(768), dim3(256), 0, stream>>>(Qb, Kb, Vt, bias_tab, maskadd, maskall, Ob);
  k_gemm<<<dim3(768), dim3(256), 0, stream>>>(Ob, Wo_t, (float*)d_out, NM, ND, ND);
}

// Round 21
// 83.474 us; speedup vs baseline: 1.1826x; 1.0093x over previous
//
#include <hip/hip_runtime.h>
#include <stdint.h>

typedef __attribute__((ext_vector_type(8))) short bf16x8;
typedef __attribute__((ext_vector_type(4))) float f32x4;
typedef __attribute__((ext_vector_type(4))) unsigned int u32x4;

#define NB 2
#define NL 2048
#define ND 768
#define NH 12
#define NDK 64
#define NM 4096   // NB*NL
#define LOG2E 1.4426950408889634f

template<int N> struct IC { static constexpr int v = N; };

__device__ __forceinline__ unsigned short f2bf(float f) {
  unsigned u = __builtin_bit_cast(unsigned, f);
  u += 0x7FFFu + ((u >> 16) & 1u);          // RNE
  return (unsigned short)(u >> 16);
}

__device__ __forceinline__ float fexp2(float x) {
  float r;
  asm("v_exp_f32 %0, %1" : "=v"(r) : "v"(x));
  return r;
}

__device__ __forceinline__ float xmax32(float x) { return fmaxf(x, __shfl_xor(x, 32)); }
__device__ __forceinline__ float xsum32(float x) { return x + __shfl_xor(x, 32); }

__device__ __forceinline__ void gl_lds16(const unsigned short* g, unsigned short* l) {
  __builtin_amdgcn_global_load_lds((const __attribute__((address_space(1))) void*)g,
                                   (__attribute__((address_space(3))) void*)l, 16, 0, 0);
}

// ---- merged prep: conv grid-stride (0..1535, 16KB/block, ILP x4) |
// wt (1536..3839) | bias (3840..4031) | maskadd (4032..4033)
__global__ __launch_bounds__(256) void k_prep(const float* __restrict__ query,
                                              const float* __restrict__ keyval,
                                              const float* __restrict__ Wq,
                                              const float* __restrict__ Wk,
                                              const float* __restrict__ Wv,
                                              const float* __restrict__ Wo,
                                              const float* __restrict__ rel_emb,
                                              const int* __restrict__ mask,
                                              unsigned short* __restrict__ q_bf,
                                              unsigned short* __restrict__ kv_bf,
                                              unsigned short* __restrict__ Wq_t,
                                              unsigned short* __restrict__ Wk_t,
                                              unsigned short* __restrict__ Wv_t,
                                              unsigned short* __restrict__ Wo_t,
                                              float* __restrict__ bias_tab,
                                              float* __restrict__ maskadd,
                                              int* __restrict__ maskall) {
  __shared__ float shbuf[32 * 33];
  int blk = blockIdx.x, tid = threadIdx.x;
  if (blk < 1536) {
    // fp32 -> bf16, 4 independent chunks per thread (ILP hides HBM latency)
    int y = blk >> 9;                       // blk/512... careful: 1536 = 2*768
    y = blk / 768;
    int base = (blk - y * 768) * 1024;
    const float* src = y ? keyval : query;
    unsigned short* dst = y ? kv_bf : q_bf;
    float4 v0 = ((const float4*)src)[base + tid];
    float4 v1 = ((const float4*)src)[base + 256 + tid];
    float4 v2 = ((const float4*)src)[base + 512 + tid];
    float4 v3 = ((const float4*)src)[base + 768 + tid];
    ushort4 o0, o1, o2, o3;
    o0.x = f2bf(v0.x); o0.y = f2bf(v0.y); o0.z = f2bf(v0.z); o0.w = f2bf(v0.w);
    o1.x = f2bf(v1.x); o1.y = f2bf(v1.y); o1.z = f2bf(v1.z); o1.w = f2bf(v1.w);
    o2.x = f2bf(v2.x); o2.y = f2bf(v2.y); o2.z = f2bf(v2.z); o2.w = f2bf(v2.w);
    o3.x = f2bf(v3.x); o3.y = f2bf(v3.y); o3.z = f2bf(v3.z); o3.w = f2bf(v3.w);
    ((ushort4*)dst)[base + tid]       = o0;
    ((ushort4*)dst)[base + 256 + tid] = o1;
    ((ushort4*)dst)[base + 512 + tid] = o2;
    ((ushort4*)dst)[base + 768 + tid] = o3;
  } else if (blk < 3840) {
    int rel = blk - 1536;
    int z = rel / 576, r2 = rel - z * 576;
    int bx = (r2 % 24) * 32, by = (r2 / 24) * 32;
    const float* w = (z == 0) ? Wq : (z == 1) ? Wk : (z == 2) ? Wv : Wo;
    unsigned short* o = (z == 0) ? Wq_t : (z == 1) ? Wk_t : (z == 2) ? Wv_t : Wo_t;
    float scale = (z == 0) ? 0.125f * LOG2E : 1.0f;
    int tx = tid & 31, ty = tid >> 5;
    float (*t)[33] = (float(*)[33])shbuf;
    for (int r = 0; r < 32; r += 8)
      t[ty + r][tx] = w[(by + ty + r) * ND + bx + tx];
    __syncthreads();
    for (int r = 0; r < 32; r += 8)
      o[(bx + ty + r) * ND + by + tx] = f2bf(t[tx][ty + r] * scale);
  } else if (blk < 4032) {
    int idx = (blk - 3840) * 256 + tid;
    if (idx >= 4095 * NH) return;
    int h = idx % NH;
    int di = idx / NH;
    int rel = di - 2047;          // rel = k - q
    int n = -rel;
    int ret = 0;
    if (n < 0) { ret = 16; n = -n; }
    int b;
    if (n < 8) {
      b = ret + n;
    } else {
      int v = (n >= 91) ? 7 : (n >= 64) ? 6 : (n >= 46) ? 5 : (n >= 32) ? 4
            : (n >= 23) ? 3 : (n >= 16) ? 2 : (n >= 12) ? 1 : 0;
      b = ret + 8 + v;
    }
    bias_tab[h * 4095 + di] = rel_emb[b * NH + h] * LOG2E;
  } else {
    int b = blk - 4032;
    int* red = (int*)shbuf;
    int acc = 1;
    for (int i = tid; i < NL; i += 256) {
      int m = mask[b * NL + i];
      maskadd[b * NL + i] = m ? 0.0f : -1e30f;
      acc &= (m != 0) ? 1 : 0;
    }
    red[tid] = acc;
    __syncthreads();
    for (int s2 = 128; s2 > 0; s2 >>= 1) {
      if (tid < s2) red[tid] &= red[tid + s2];
      __syncthreads();
    }
    if (tid == 0) maskall[b] = red[0];
  }
}

// ---- fused QKV GEMM, 128x96 tile, grid (32,24) = 768 = 3/CU. A-only double
// buffer: A(t+1) issued before compute(t); B (L2-hot) staged after the barrier.
__global__ __launch_bounds__(256) void k_gemm_qkv(const unsigned short* __restrict__ q_bf,
                                                  const unsigned short* __restrict__ kv_bf,
                                                  const unsigned short* __restrict__ Wt,
                                                  unsigned short* __restrict__ Qb,
                                                  unsigned short* __restrict__ Kb,
                                                  unsigned short* __restrict__ Vt) {
  __shared__ unsigned short S[22528];   // A0:[0,8192) A1:[8192,16384) B:[16384,22528)
  unsigned short* Bs = S + 16384;
  int tid = threadIdx.x;
  int wave = tid >> 6, lane = tid & 63;
  int lr = lane & 15, lg = lane >> 4;
  int m0 = blockIdx.x * 128;
  int z = blockIdx.y >> 3;                 // 0=Q, 1=K, 2=V
  int nc0 = (blockIdx.y & 7) * 96;         // col within the 768-wide section
  const unsigned short* A  = (z == 0) ? q_bf : kv_bf;
  const unsigned short* Bt = Wt + (size_t)blockIdx.y * 96 * ND;
  int wm = (wave >> 1) * 64, wn = (wave & 1) * 48;
  int srow = tid >> 3, spc = tid & 7;
  int sg = spc ^ (srow & 7);
  const unsigned short* Ag = A  + (size_t)(m0 + srow) * ND + sg * 8;
  const unsigned short* Bg = Bt + (size_t)srow * ND + sg * 8;
  f32x4 acc[4][3] = {};
  const int KT = ND / 64;
#pragma unroll
  for (int s = 0; s < 4; ++s)
    gl_lds16(Ag + (size_t)(s * 32) * ND, &S[s * 2048 + tid * 8]);
#pragma unroll
  for (int s = 0; s < 3; ++s)
    gl_lds16(Bg + (size_t)(s * 32) * ND, &Bs[s * 2048 + tid * 8]);
  __syncthreads();
  int cur = 0;
  for (int t = 0; t < KT; ++t) {
    unsigned short* Acur = S + (cur ? 8192 : 0);
    unsigned short* Anxt = S + (cur ? 0 : 8192);
    if (t + 1 < KT) {                       // A(t+1) flies under compute(t)
      int k0 = (t + 1) * 64;
#pragma unroll
      for (int s = 0; s < 4; ++s)
        gl_lds16(Ag + (size_t)(s * 32) * ND + k0, &Anxt[s * 2048 + tid * 8]);
    }
#pragma unroll
    for (int ks = 0; ks < 2; ++ks) {
      bf16x8 af[4], bfr[3];
#pragma unroll
      for (int i = 0; i < 4; ++i) {
        int ar = wm + i * 16 + lr;
        af[i] = *(const bf16x8*)&Acur[ar * 64 + (((ks * 4 + lg) ^ (ar & 7)) * 8)];
      }
#pragma unroll
      for (int i = 0; i < 3; ++i) {
        int br = wn + i * 16 + lr;
        bfr[i] = *(const bf16x8*)&Bs[br * 64 + (((ks * 4 + lg) ^ (br & 7)) * 8)];
      }
#pragma unroll
      for (int mi = 0; mi < 4; ++mi)
#pragma unroll
        for (int ni = 0; ni < 3; ++ni)
          acc[mi][ni] = __builtin_amdgcn_mfma_f32_16x16x32_bf16(af[mi], bfr[ni], acc[mi][ni], 0, 0, 0);
    }
    __syncthreads();                        // A(t+1) complete; Bs reads done
    if (t + 1 < KT) {                       // B(t+1): L2-hot, short wait
      int k0 = (t + 1) * 64;
#pragma unroll
      for (int s = 0; s < 3; ++s)
        gl_lds16(Bg + (size_t)(s * 32) * ND + k0, &Bs[s * 2048 + tid * 8]);
      asm volatile("s_waitcnt vmcnt(0)" ::: "memory");
      __builtin_amdgcn_s_barrier();
    }
    cur ^= 1;
  }
  if (z == 2) {
    unsigned short* T = S;
#pragma unroll
    for (int mi = 0; mi < 4; ++mi)
#pragma unroll
      for (int ni = 0; ni < 3; ++ni) {
        int col  = wn + ni * 16 + lr;
        int rowb = wm + mi * 16 + lg * 4;
        ushort4 v4;
        v4.x = f2bf(acc[mi][ni][0]);
        v4.y = f2bf(acc[mi][ni][1]);
        v4.z = f2bf(acc[mi][ni][2]);
        v4.w = f2bf(acc[mi][ni][3]);
        int addr = col * 128 + (((rowb >> 3) ^ (col & 7)) * 8) + (rowb & 7);
        *(ushort4*)&T[addr] = v4;
      }
    __syncthreads();
    int bb = m0 >> 11;
    unsigned short* vdst = Vt + (((size_t)bb * ND + nc0) << 11) + (m0 & 2047);
#pragma unroll
    for (int pass = 0; pass < 6; ++pass) {
      int col = (tid >> 4) + pass * 16;
      int cc = tid & 15;
      u32x4 val = *(const u32x4*)&T[col * 128 + ((cc ^ (col & 7)) * 8)];
      *(u32x4*)&vdst[((size_t)col << 11) + cc * 8] = val;
    }
  } else {
#pragma unroll
    for (int mi = 0; mi < 4; ++mi)
#pragma unroll
      for (int ni = 0; ni < 3; ++ni)
#pragma unroll
        for (int r = 0; r < 4; ++r) {
          int row = m0 + wm + mi * 16 + lg * 4 + r;
          int col = nc0 + wn + ni * 16 + lr;
          unsigned short v = f2bf(acc[mi][ni][r]);
          if (z == 0) Qb[(size_t)row * ND + col] = v;
          else        Kb[(size_t)row * ND + col] = v;
        }
  }
}

// ---- out-proj GEMM: C[M,N] fp32 = A[M,K] bf16 * Bt[N,K]^T. 64x64 tile, flat grid
// 768 + XCD swizzle + dbuf LDS with prefetch-before-compute.
__global__ __launch_bounds__(256) void k_gemm(const unsigned short* __restrict__ A,
                                              const unsigned short* __restrict__ Bt,
                                              float* __restrict__ Cout,
                                              int Msz, int Nsz, int Ksz) {
  __shared__ unsigned short As[2][4096];
  __shared__ unsigned short Bs[2][4096];
  int flat = blockIdx.x;
  int nf = (flat & 7) * 96 + (flat >> 3);
  int px = nf / 12;
  int y  = nf - px * 12;
  int tid = threadIdx.x;
  int wave = tid >> 6, lane = tid & 63;
  int lr = lane & 15, lg = lane >> 4;
  int m0 = px * 64, n0 = y * 64;
  int wm = (wave >> 1) * 32, wn = (wave & 1) * 32;
  int srow = tid >> 3, spc = tid & 7;
  int sg = spc ^ (srow & 7);
  const unsigned short* Ag = A  + (size_t)(m0 + srow) * Ksz + sg * 8;
  const unsigned short* Bg = Bt + (size_t)(n0 + srow) * Ksz + sg * 8;
  f32x4 acc[2][2] = {};
  const int KT = Ksz >> 6;
#pragma unroll
  for (int s = 0; s < 2; ++s) {
    gl_lds16(Ag + (size_t)(s * 32) * Ksz, &As[0][s * 2048 + tid * 8]);
    gl_lds16(Bg + (size_t)(s * 32) * Ksz, &Bs[0][s * 2048 + tid * 8]);
  }
  __syncthreads();
  int cur = 0;
  for (int t = 0; t < KT; ++t) {
    if (t + 1 < KT) {
      int k0 = (t + 1) << 6;
#pragma unroll
      for (int s = 0; s < 2; ++s) {
        gl_lds16(Ag + (size_t)(s * 32) * Ksz + k0, &As[cur ^ 1][s * 2048 + tid * 8]);
        gl_lds16(Bg + (size_t)(s * 32) * Ksz + k0, &Bs[cur ^ 1][s * 2048 + tid * 8]);
      }
    }
#pragma unroll
    for (int ks = 0; ks < 2; ++ks) {
      bf16x8 af[2], bfr[2];
#pragma unroll
      for (int i = 0; i < 2; ++i) {
        int ar = wm + i * 16 + lr;
        af[i] = *(const bf16x8*)&As[cur][ar * 64 + (((ks * 4 + lg) ^ (ar & 7)) * 8)];
        int br = wn + i * 16 + lr;
        bfr[i] = *(const bf16x8*)&Bs[cur][br * 64 + (((ks * 4 + lg) ^ (br & 7)) * 8)];
      }
#pragma unroll
      for (int mi = 0; mi < 2; ++mi)
#pragma unroll
        for (int ni = 0; ni < 2; ++ni)
          acc[mi][ni] = __builtin_amdgcn_mfma_f32_16x16x32_bf16(af[mi], bfr[ni], acc[mi][ni], 0, 0, 0);
    }
    __syncthreads();
    cur ^= 1;
  }
#pragma unroll
  for (int mi = 0; mi < 2; ++mi)
#pragma unroll
    for (int ni = 0; ni < 2; ++ni)
#pragma unroll
      for (int r = 0; r < 4; ++r) {
        int row = m0 + wm + mi * 16 + lg * 4 + r;
        int col = n0 + wn + ni * 16 + lr;
        Cout[(size_t)row * Nsz + col] = acc[mi][ni][r];
      }
}

// ---- fused flash attention (R20 structure): swapped-QK^T (exp2), 3-buffer
// counted-vmcnt pipeline, far-tile zero-C bias, lane-local softmax, XCD swizzle.
__global__ __launch_bounds__(256, 3) void k_attn(const unsigned short* __restrict__ Qb,
                                                 const unsigned short* __restrict__ Kb,
                                                 const unsigned short* __restrict__ Vt,
                                                 const float* __restrict__ bias_tab,
                                                 const float* __restrict__ maskadd,
                                                 const int* __restrict__ maskall,
                                                 unsigned short* __restrict__ Ob) {
  __shared__ unsigned short Ks[3][4096];
  __shared__ unsigned short Vs[3][4096];
  __shared__ float biasw[384];
  int flat = blockIdx.x;
  int nf = (flat & 7) * 96 + (flat >> 3);
  int qt = nf & 31, bh = nf >> 5;
  int b = bh / NH, h = bh % NH;
  int tid = threadIdx.x, wave = tid >> 6, lane = tid & 63;
  int lr = lane & 15, lg = lane >> 4;
  int q0 = qt * 64;
  for (int i = tid; i < 383; i += 256) biasw[i] = bias_tab[h * 4095 + 1856 + i];
  float cFlo = bias_tab[h * 4095];
  float cFhi = bias_tab[h * 4095 + 4094];
  const unsigned short* Kbase = Kb + (size_t)(b * NL) * ND + h * NDK;
  const unsigned short* Vbase = Vt + (size_t)(b * NH + h) * NDK * NL;
  int srow = tid >> 3, spc = tid & 7;
  int sg = spc ^ (srow & 7);
  int l0 = (srow >> 4) * 32 + ((srow >> 2) & 3) * 8 + (srow & 3);
  const unsigned short* Kg0 = Kbase + (size_t)l0 * ND + sg * 8;
  const unsigned short* Kg1 = Kbase + (size_t)(l0 + 4) * ND + sg * 8;
  const unsigned short* Vg0 = Vbase + (size_t)srow * NL + sg * 8;
  const unsigned short* Vg1 = Vbase + (size_t)(32 + srow) * NL + sg * 8;
  bf16x8 aq[2];
  int qw = q0 + wave * 16;
#pragma unroll
  for (int ks = 0; ks < 2; ++ks)
    aq[ks] = *(const bf16x8*)&Qb[(size_t)(b * NL + qw + lr) * ND + h * NDK + ks * 32 + lg * 8];
  const float* cbase = maskadd + b * NL;
  int nomask = __builtin_amdgcn_readfirstlane(maskall[b]);
  f32x4 accO[4] = {};
  float mst = -1e30f, lstl = 0.f;
  int bconst = lg * 8 - wave * 16 - lr + 191 - q0;
  int src0 = (lane & 48) | ((lane >> 2) & 12);
  gl_lds16(Kg0, &Ks[0][tid * 8]);
  gl_lds16(Kg1, &Ks[0][2048 + tid * 8]);
  gl_lds16(Vg0, &Vs[0][tid * 8]);
  gl_lds16(Vg1, &Vs[0][2048 + tid * 8]);
  {
    size_t kok = (size_t)64 * ND, kov = 64;
    gl_lds16(Kg0 + kok, &Ks[1][tid * 8]);
    gl_lds16(Kg1 + kok, &Ks[1][2048 + tid * 8]);
    gl_lds16(Vg0 + kov, &Vs[1][tid * 8]);
    gl_lds16(Vg1 + kov, &Vs[1][2048 + tid * 8]);
  }
  asm volatile("s_waitcnt vmcnt(4) lgkmcnt(0)" ::: "memory");
  __builtin_amdgcn_s_barrier();
  const unsigned short* sk0 = Kg0 + (size_t)2 * 64 * ND;
  const unsigned short* sk1 = Kg1 + (size_t)2 * 64 * ND;
  const unsigned short* sv0 = Vg0 + 2 * 64;
  const unsigned short* sv1 = Vg1 + 2 * 64;

  auto body = [&](int kt_, auto CURc, auto PFc) {
    constexpr int CUR = decltype(CURc)::v;
    constexpr int PF  = decltype(PFc)::v;
    constexpr int ST  = (CUR + 2) % 3;
    float4 cv[2][2];
    if (!nomask) {
#pragma unroll
      for (int hf = 0; hf < 2; ++hf)
#pragma unroll
        for (int qd = 0; qd < 2; ++qd)
          cv[hf][qd] = *(const float4*)&cbase[kt_ * 64 + hf * 32 + lg * 8 + qd * 4];
    }
    if (PF) {
      gl_lds16(sk0, &Ks[ST][tid * 8]);
      gl_lds16(sk1, &Ks[ST][2048 + tid * 8]);
      gl_lds16(sv0, &Vs[ST][tid * 8]);
      gl_lds16(sv1, &Vs[ST][2048 + tid * 8]);
      sk0 += 64 * ND; sk1 += 64 * ND; sv0 += 64; sv1 += 64;
    }
    int kt64 = kt_ * 64;
    bool farlo = (kt64 + 63 < q0 - 90), farhi = (kt64 > q0 + 153);
    float ctile = farlo ? cFlo : (farhi ? cFhi : 0.0f);
    f32x4 s[4];
    if (nomask && (farlo || farhi)) {
      const f32x4 z = {0.f, 0.f, 0.f, 0.f};
#pragma unroll
      for (int ni = 0; ni < 4; ++ni) {
        int kr = ni * 16 + lr;
        bf16x8 bk0 = *(const bf16x8*)&Ks[CUR][kr * 64 + ((lg ^ (lr & 7)) * 8)];
        bf16x8 bk1 = *(const bf16x8*)&Ks[CUR][kr * 64 + (((4 + lg) ^ (lr & 7)) * 8)];
        s[ni] = __builtin_amdgcn_mfma_f32_16x16x32_bf16(bk0, aq[0], z, 0, 0, 0);
        s[ni] = __builtin_amdgcn_mfma_f32_16x16x32_bf16(bk1, aq[1], s[ni], 0, 0, 0);
      }
    } else {
      if (farlo || farhi) {
#pragma unroll
        for (int ni = 0; ni < 4; ++ni)
#pragma unroll
          for (int r = 0; r < 4; ++r) s[ni][r] = 0.f;
      } else {
#pragma unroll
        for (int ni = 0; ni < 4; ++ni)
#pragma unroll
          for (int r = 0; r < 4; ++r)
            s[ni][r] = biasw[kt64 + (ni & 1) * 32 + (ni >> 1) * 4 + r + bconst];
      }
      if (!nomask) {
#pragma unroll
        for (int ni = 0; ni < 4; ++ni)
#pragma unroll
          for (int r = 0; r < 4; ++r)
            s[ni][r] += ((const float*)&cv[ni & 1][ni >> 1])[r];
      }
#pragma unroll
      for (int ni = 0; ni < 4; ++ni) {
        int kr = ni * 16 + lr;
        bf16x8 bk0 = *(const bf16x8*)&Ks[CUR][kr * 64 + ((lg ^ (lr & 7)) * 8)];
        bf16x8 bk1 = *(const bf16x8*)&Ks[CUR][kr * 64 + (((4 + lg) ^ (lr & 7)) * 8)];
        s[ni] = __builtin_amdgcn_mfma_f32_16x16x32_bf16(bk0, aq[0], s[ni], 0, 0, 0);
        s[ni] = __builtin_amdgcn_mfma_f32_16x16x32_bf16(bk1, aq[1], s[ni], 0, 0, 0);
      }
    }
    float a0 = fmaxf(fmaxf(s[0][0], s[0][1]), s[0][2]);
    float a1 = fmaxf(fmaxf(s[0][3], s[1][0]), s[1][1]);
    float a2 = fmaxf(fmaxf(s[1][2], s[1][3]), s[2][0]);
    float a3 = fmaxf(fmaxf(s[2][1], s[2][2]), s[2][3]);
    float a4 = fmaxf(fmaxf(s[3][0], s[3][1]), s[3][2]);
    float lm = fmaxf(fmaxf(fmaxf(a0, a1), a2), fmaxf(fmaxf(a3, a4), s[3][3]));
    if (!__all(lm + ctile - mst <= 8.0f)) {
      float pmax = fmaxf(lm, __shfl_xor(lm, 16));
      pmax = xmax32(pmax);
      float pm2 = pmax + ctile;
      float mnew = fmaxf(mst, pm2);
      float sc = fexp2(mst - mnew);
      float scB[4];
#pragma unroll
      for (int r = 0; r < 4; ++r) scB[r] = __shfl(sc, src0 | r);
#pragma unroll
      for (int ni = 0; ni < 4; ++ni)
#pragma unroll
        for (int r = 0; r < 4; ++r) accO[ni][r] *= scB[r];
      lstl *= sc;
      mst = mnew;
    }
    float msub = mst - ctile;
#pragma unroll
    for (int ni = 0; ni < 4; ++ni)
#pragma unroll
      for (int r = 0; r < 4; ++r) s[ni][r] = fexp2(s[ni][r] - msub);
    {
      f32x4 ta = s[0] + s[1];
      f32x4 tb = s[2] + s[3];
      ta = ta + tb;
      lstl += (ta[0] + ta[1]) + (ta[2] + ta[3]);
    }
    unsigned pw[8];
#pragma unroll
    for (int ni = 0; ni < 4; ++ni) {
      unsigned a, c;
      asm("v_cvt_pk_bf16_f32 %0, %1, %2" : "=v"(a) : "v"(s[ni][0]), "v"(s[ni][1]));
      asm("v_cvt_pk_bf16_f32 %0, %1, %2" : "=v"(c) : "v"(s[ni][2]), "v"(s[ni][3]));
      pw[ni * 2] = a; pw[ni * 2 + 1] = c;
    }
    u32x4 apw0 = {pw[0], pw[1], pw[4], pw[5]};
    u32x4 apw1 = {pw[2], pw[3], pw[6], pw[7]};
    bf16x8 ap0 = __builtin_bit_cast(bf16x8, apw0);
    bf16x8 ap1 = __builtin_bit_cast(bf16x8, apw1);
#pragma unroll
    for (int ni = 0; ni < 4; ++ni) {
      int vr = ni * 16 + lr;
      bf16x8 bv0 = *(const bf16x8*)&Vs[CUR][vr * 64 + ((lg ^ (lr & 7)) * 8)];
      bf16x8 bv1 = *(const bf16x8*)&Vs[CUR][vr * 64 + (((4 + lg) ^ (lr & 7)) * 8)];
      accO[ni] = __builtin_amdgcn_mfma_f32_16x16x32_bf16(ap0, bv0, accO[ni], 0, 0, 0);
      accO[ni] = __builtin_amdgcn_mfma_f32_16x16x32_bf16(ap1, bv1, accO[ni], 0, 0, 0);
    }
    if (PF) asm volatile("s_waitcnt vmcnt(4)" ::: "memory");
    else    asm volatile("s_waitcnt vmcnt(0)" ::: "memory");
    __builtin_amdgcn_s_barrier();
  };

  for (int kt = 0; kt < 30; kt += 3) {
    body(kt,     IC<0>{}, IC<1>{});
    body(kt + 1, IC<1>{}, IC<1>{});
    body(kt + 2, IC<2>{}, IC<1>{});
  }
  body(30, IC<0>{}, IC<0>{});
  body(31, IC<1>{}, IC<0>{});

  float lst = lstl + __shfl_xor(lstl, 16);
  lst = xsum32(lst);
  float linv = 1.0f / lst;
  float lB[4];
#pragma unroll
  for (int r = 0; r < 4; ++r) lB[r] = __shfl(linv, src0 | r);
#pragma unroll
  for (int ni = 0; ni < 4; ++ni)
#pragma unroll
    for (int r = 0; r < 4; ++r) {
      int qg = qw + lg * 4 + r;
      int col = h * NDK + ni * 16 + lr;
      Ob[(size_t)(b * NL + qg) * ND + col] = f2bf(accO[ni][r] * lB[r]);
    }
}

extern "C" void kernel_launch(void* const* d_in, const int* in_sizes, int n_in,
                              void* d_out, int out_size, void* d_ws, size_t ws_size,
                              hipStream_t stream) {
  const float* query  = (const float*)d_in[0];
  const float* keyval = (const float*)d_in[1];
  const int*   mask   = (const int*)d_in[2];
  const float* Wq     = (const float*)d_in[3];
  const float* Wk     = (const float*)d_in[4];
  const float* Wv     = (const float*)d_in[5];
  const float* Wo     = (const float*)d_in[6];
  const float* rel    = (const float*)d_in[7];

  char* ws = (char*)d_ws;
  unsigned short* q_bf  = (unsigned short*)(ws);              // 4096x768 bf16
  unsigned short* kv_bf = (unsigned short*)(ws + 6291456);
  unsigned short* Wq_t  = (unsigned short*)(ws + 12582912);   // [N][K] bf16 (x 0.125*log2e)
  unsigned short* Wk_t  = (unsigned short*)(ws + 13762560);
  unsigned short* Wv_t  = (unsigned short*)(ws + 14942208);
  unsigned short* Wo_t  = (unsigned short*)(ws + 16121856);
  unsigned short* Qb    = (unsigned short*)(ws + 17301504);   // [B,L,H,DK]
  unsigned short* Kb    = (unsigned short*)(ws + 23592960);
  unsigned short* Vt    = (unsigned short*)(ws + 29884416);   // [B,768,L]
  unsigned short* Ob    = (unsigned short*)(ws + 36175872);   // [B,L,H*DK]
  float* bias_tab       = (float*)(ws + 42467328);            // [H][4095], x log2e
  float* maskadd        = (float*)(ws + 42663936);            // [B][L]
  int*   maskall        = (int*)(ws + 42680320);              // [B]

  k_prep<<<dim3(4034), dim3(256), 0, stream>>>(query, keyval, Wq, Wk, Wv, Wo, rel, mask,
                                               q_bf, kv_bf, Wq_t, Wk_t, Wv_t, Wo_t,
                                               bias_tab, maskadd, maskall);
  k_gemm_qkv<<<dim3(32, 24), dim3(256), 0, stream>>>(q_bf, kv_bf, Wq_t, Qb, Kb, Vt);
  k_attn<<<dim3(768), dim3(256), 0, stream>>>(Qb, Kb, Vt, bias_tab, maskadd, maskall, Ob);
  k_gemm<<<dim3(768), dim3(256), 0, stream>>>(Ob, Wo_t, (float*)d_out, NM, ND, ND);
}